// Round 22
// baseline (812.548 us; speedup 1.0000x reference)
//
#include <hip/hip_runtime.h>
#include <stdint.h>

typedef unsigned short u16;
typedef unsigned int   u32;
typedef __attribute__((ext_vector_type(4))) float     f32x4;
typedef __attribute__((ext_vector_type(8))) _Float16  f16x8;

#define S_LEN 1024
#define NB    2
#define H_DIM 2048
#define T_TOK 2048
#define NHEAD 16
#define NKVH  4
#define DHEAD 128
#define NEXP  16
#define FFE   1408
#define FF2   2816
#define EPSF  1e-5f
#define RSF_C 1.0f

// ---- f32 <-> f16 helpers (scaled hi/lo split: x ~= hi + lo/2048) ----
__device__ __forceinline__ u16 f2h(float f){
  _Float16 h = (_Float16)f;
  return __builtin_bit_cast(unsigned short, h);
}
__device__ __forceinline__ void split2(float f, u16& hi, u16& lo){
  _Float16 h = (_Float16)f;
  hi = __builtin_bit_cast(unsigned short, h);
  _Float16 l = (_Float16)((f - (float)h) * 2048.0f);
  lo = __builtin_bit_cast(unsigned short, l);
}
__device__ __forceinline__ void gload_lds16(const void* g, void* l){
  __builtin_amdgcn_global_load_lds((const __attribute__((address_space(1))) void*)g,
                                   (__attribute__((address_space(3))) void*)l, 16, 0, 0);
}
__device__ __forceinline__ uint4 pack8(const u16* p){
  return make_uint4((u32)p[0] | ((u32)p[1]<<16), (u32)p[2] | ((u32)p[3]<<16),
                    (u32)p[4] | ((u32)p[5]<<16), (u32)p[6] | ((u32)p[7]<<16));
}

// ---- shared tsplit body (64x64 f32 tile transpose -> u16 hi/lo), LDS passed in ----
__device__ __forceinline__ void tsplit_body(
    const float* __restrict__ in, int ldn,
    u16* __restrict__ outh, u16* __restrict__ outl, int ldk, bool dual,
    void* smem)
{
  float (*tile)[65] = (float(*)[65])smem;
  const int n0 = blockIdx.x * 64, k0 = blockIdx.y * 64;
  const int tid = threadIdx.x;
  const int tr = tid >> 4, tc = (tid & 15) * 4;
  #pragma unroll
  for (int i = 0; i < 4; i++) {
    float4 v = *(const float4*)&in[(size_t)(k0 + tr + i*16) * ldn + (n0 + tc)];
    tile[tr + i*16][tc+0] = v.x; tile[tr + i*16][tc+1] = v.y;
    tile[tr + i*16][tc+2] = v.z; tile[tr + i*16][tc+3] = v.w;
  }
  __syncthreads();
  const int n = tid >> 2, kg = (tid & 3) * 16;
  u16 hb[16], lb[16];
  #pragma unroll
  for (int j = 0; j < 16; j++) {
    float f = tile[kg + j][n];
    if (dual) split2(f, hb[j], lb[j]); else hb[j] = f2h(f);
  }
  u16* dh = &outh[(size_t)(n0 + n) * ldk + k0 + kg];
  *(uint4*)dh       = pack8(hb);
  *(uint4*)(dh + 8) = pack8(hb + 8);
  if (dual) {
    u16* dl = &outl[(size_t)(n0 + n) * ldk + k0 + kg];
    *(uint4*)dl       = pack8(lb);
    *(uint4*)(dl + 8) = pack8(lb + 8);
  }
}

// ---------------- tsplit_qkv: wq/wk/wv transpose/split (needed before qkv gemm) ----------------
// grid (32,32,3): z=0 wq, z=1 wk, z=2 wv.
__global__ __launch_bounds__(256) void tsplit_all_kernel(
    const float* __restrict__ wq, const float* __restrict__ wk,
    const float* __restrict__ wv,
    u16* __restrict__ wqkvh, u16* __restrict__ wqkvl)
{
  const int z = blockIdx.z;
  const float* in; int ldn; u16* outh; u16* outl; int nx;
  switch (z) {
    case 0:  in=wq;  ldn=2048; outh=wqkvh;            outl=wqkvl;            nx=32; break;
    case 1:  in=wk;  ldn=512;  outh=wqkvh+2048*2048;  outl=wqkvl+2048*2048;  nx=8;  break;
    default: in=wv;  ldn=512;  outh=wqkvh+2560*2048;  outl=wqkvl+2560*2048;  nx=8;  break;
  }
  if ((int)blockIdx.x >= nx) return;
  __shared__ __align__(16) char smem[16704];
  tsplit_body(in, ldn, outh, outl, 2048, true, smem);
}

// ---------------- RMSNorm: f32 in -> f16 hi (+optional scaled lo) ----------------
__global__ __launch_bounds__(256) void rmsnorm_kernel(
    const float* __restrict__ in, const float* __restrict__ w,
    u16* __restrict__ outh, u16* __restrict__ outl)
{
  __shared__ float red[4];
  const int t = blockIdx.x, tid = threadIdx.x;
  const int lane = tid & 63, wave = tid >> 6;
  const float* x = in + (size_t)t * H_DIM;
  const int c = tid * 8;
  float4 v0 = *(const float4*)&x[c];
  float4 v1 = *(const float4*)&x[c + 4];
  float ss = v0.x*v0.x + v0.y*v0.y + v0.z*v0.z + v0.w*v0.w
           + v1.x*v1.x + v1.y*v1.y + v1.z*v1.z + v1.w*v1.w;
  #pragma unroll
  for (int d = 1; d < 64; d <<= 1) ss += __shfl_xor(ss, d, 64);
  if (lane == 0) red[wave] = ss;
  __syncthreads();
  float rinv = rsqrtf((red[0]+red[1]+red[2]+red[3]) * (1.0f/H_DIM) + EPSF);
  float4 w0 = *(const float4*)&w[c];
  float4 w1 = *(const float4*)&w[c + 4];
  float vals[8] = { v0.x*rinv*w0.x, v0.y*rinv*w0.y, v0.z*rinv*w0.z, v0.w*rinv*w0.w,
                    v1.x*rinv*w1.x, v1.y*rinv*w1.y, v1.z*rinv*w1.z, v1.w*rinv*w1.w };
  u16 hb[8], lb[8];
  #pragma unroll
  for (int j = 0; j < 8; j++) split2(vals[j], hb[j], lb[j]);
  *(uint4*)&outh[(size_t)t * H_DIM + c] = pack8(hb);
  if (outl) *(uint4*)&outl[(size_t)t * H_DIM + c] = pack8(lb);
}

// ---------------- gemm3b: C(f32) = (Ah+Al/2048) @ (Bh+Bl/2048)^T; BK=64, swizzled LDS ----------------
__global__ __launch_bounds__(256) void gemm3b_kernel(
    const u16* __restrict__ Ah, const u16* __restrict__ Al, int lda,
    const u16* __restrict__ Bh, const u16* __restrict__ Bl, int ldb,
    float* __restrict__ C, int ldc,
    const float* __restrict__ addsrc, int K)
{
  __shared__ u16 Ash[128*64], Asl[128*64];
  __shared__ u16 Bsh[128*64], Bsl[128*64];
  const int tid = threadIdx.x, lane = tid & 63, wave = tid >> 6;
  const int m0 = blockIdx.y * 128, n0 = blockIdx.x * 128;
  const int wm = (wave >> 1) * 64, wn = (wave & 1) * 64;
  const int arow = lane >> 3;
  const int acol = ((lane & 7) ^ arow) * 8;
  f32x4 acc0[4][4] = {}, acc1[4][4] = {};
  for (int k0 = 0; k0 < K; k0 += 64) {
    #pragma unroll
    for (int g = 0; g < 4; g++) {
      const int rb = wave*32 + g*8;
      gload_lds16(Ah + (size_t)(m0 + rb + arow)*lda + k0 + acol, &Ash[rb*64]);
      gload_lds16(Al + (size_t)(m0 + rb + arow)*lda + k0 + acol, &Asl[rb*64]);
      gload_lds16(Bh + (size_t)(n0 + rb + arow)*ldb + k0 + acol, &Bsh[rb*64]);
      gload_lds16(Bl + (size_t)(n0 + rb + arow)*ldb + k0 + acol, &Bsl[rb*64]);
    }
    asm volatile("s_waitcnt vmcnt(0) lgkmcnt(0)" ::: "memory");
    __syncthreads();
    const int fr = lane & 15, fg = lane >> 4;
    #pragma unroll
    for (int kk = 0; kk < 2; kk++) {
      const int cb = fg + kk*4;
      f16x8 ah[4], al[4];
      #pragma unroll
      for (int m = 0; m < 4; m++) {
        const int r = wm + m*16 + fr;
        const int s = (cb ^ (r & 7)) * 8;
        ah[m] = *(const f16x8*)&Ash[r*64 + s];
        al[m] = *(const f16x8*)&Asl[r*64 + s];
      }
      #pragma unroll
      for (int n = 0; n < 4; n++) {
        const int r = wn + n*16 + fr;
        const int s = (cb ^ (r & 7)) * 8;
        f16x8 bh_ = *(const f16x8*)&Bsh[r*64 + s];
        f16x8 bl_ = *(const f16x8*)&Bsl[r*64 + s];
        #pragma unroll
        for (int m = 0; m < 4; m++) {
          acc0[m][n] = __builtin_amdgcn_mfma_f32_16x16x32_f16(ah[m], bh_, acc0[m][n], 0,0,0);
          acc1[m][n] = __builtin_amdgcn_mfma_f32_16x16x32_f16(ah[m], bl_, acc1[m][n], 0,0,0);
          acc1[m][n] = __builtin_amdgcn_mfma_f32_16x16x32_f16(al[m], bh_, acc1[m][n], 0,0,0);
        }
      }
    }
    __syncthreads();
  }
  const int cr = (lane >> 4) * 4, cc = lane & 15;
  #pragma unroll
  for (int m = 0; m < 4; m++)
    #pragma unroll
    for (int n = 0; n < 4; n++)
      #pragma unroll
      for (int j = 0; j < 4; j++) {
        int r = m0 + wm + m*16 + cr + j;
        size_t idx = (size_t)r * ldc + (n0 + wn + n*16 + cc);
        float v = acc0[m][n][j] + acc1[m][n][j] * (1.0f/2048.0f);
        if (addsrc) v += addsrc[idx];
        C[idx] = v;
      }
}

// ---------------- gemm_up_all: expert up (tile queue, indirect A via list, f32 B) + shared up (dense, u16 B) ----------------
// grid (44, 1, 40): z<32 -> expert tile z; z>=32 -> shared m-tile (z-32). M=256 x N=64, BK=64.
__global__ __launch_bounds__(256) void gemm_up_all_kernel(
    const int* __restrict__ list, const float* __restrict__ egu, float* __restrict__ gu_exp,
    const int* __restrict__ counts, const int* __restrict__ offs,
    const int* __restrict__ tile_e, const int* __restrict__ tile_m0,
    const u16* __restrict__ tok, const u16* __restrict__ sgut, float* __restrict__ gu_sh)
{
  __shared__ u16 As[256*64];
  __shared__ u16 Bs[64*64];
  const int z = blockIdx.z;
  const int tid = threadIdx.x, lane = tid & 63, wave = tid >> 6;
  const int n0 = blockIdx.x * 64;
  const int wm = wave * 64;
  const int arow = lane >> 3;
  const int acol = ((lane & 7) ^ arow) * 8;
  const int fr = lane & 15, fg = lane >> 4;
  const int cr = (lane >> 4) * 4, cc = lane & 15;

  if (z < 32) {
    const int e = tile_e[z];
    if (e < 0) return;
    const int m0 = tile_m0[z];
    const int cnt = counts[e];
    const int off = offs[e];
    const float* B = egu + (size_t)e * H_DIM * FF2;
    float* C = gu_exp + (size_t)off * FF2;
    const u16* arp[8];
    #pragma unroll
    for (int g = 0; g < 8; g++) {
      int idx = off + m0 + wm + g*8 + arow;
      if (idx > 2*T_TOK - 1) idx = 2*T_TOK - 1;
      arp[g] = tok + (size_t)list[idx] * H_DIM + acol;
    }
    const int bn  = tid & 63;
    const int bkb = tid >> 6;
    const int bs0 = bn*64 + (((bkb*2)     ^ (bn & 7)) * 8);
    const int bs1 = bn*64 + (((bkb*2 + 1) ^ (bn & 7)) * 8);
    f32x4 acc[4][4] = {};
    for (int k0 = 0; k0 < H_DIM; k0 += 64) {
      #pragma unroll
      for (int g = 0; g < 8; g++)
        gload_lds16(arp[g] + k0, &As[(wm + g*8)*64]);
      {
        const float* gb = B + (size_t)(k0 + bkb*16) * FF2 + (n0 + bn);
        float f[16];
        #pragma unroll
        for (int j = 0; j < 16; j++) f[j] = gb[(size_t)j * FF2];
        u32 pk[8];
        #pragma unroll
        for (int j = 0; j < 8; j++)
          pk[j] = __builtin_bit_cast(u32, __builtin_amdgcn_cvt_pkrtz(f[2*j], f[2*j+1]));
        *(uint4*)&Bs[bs0] = make_uint4(pk[0], pk[1], pk[2], pk[3]);
        *(uint4*)&Bs[bs1] = make_uint4(pk[4], pk[5], pk[6], pk[7]);
      }
      asm volatile("s_waitcnt vmcnt(0) lgkmcnt(0)" ::: "memory");
      __syncthreads();
      #pragma unroll
      for (int kk = 0; kk < 2; kk++) {
        const int cb = fg + kk*4;
        f16x8 a[4], b[4];
        #pragma unroll
        for (int m = 0; m < 4; m++) {
          const int r = wm + m*16 + fr;
          a[m] = *(const f16x8*)&As[r*64 + ((cb ^ (r & 7)) * 8)];
        }
        #pragma unroll
        for (int n = 0; n < 4; n++) {
          const int r = n*16 + fr;
          b[n] = *(const f16x8*)&Bs[r*64 + ((cb ^ (r & 7)) * 8)];
        }
        #pragma unroll
        for (int n = 0; n < 4; n++)
          #pragma unroll
          for (int m = 0; m < 4; m++)
            acc[m][n] = __builtin_amdgcn_mfma_f32_16x16x32_f16(a[m], b[n], acc[m][n], 0,0,0);
      }
      __syncthreads();
    }
    #pragma unroll
    for (int m = 0; m < 4; m++)
      #pragma unroll
      for (int n = 0; n < 4; n++)
        #pragma unroll
        for (int j = 0; j < 4; j++) {
          int r = m0 + wm + m*16 + cr + j;
          if (r < cnt) C[(size_t)r * FF2 + (n0 + n*16 + cc)] = acc[m][n][j];
        }
  } else {
    const int m0 = (z - 32) * 256;
    f32x4 acc[4][4] = {};
    for (int k0 = 0; k0 < H_DIM; k0 += 64) {
      #pragma unroll
      for (int g = 0; g < 8; g++)
        gload_lds16(tok + (size_t)(m0 + wm + g*8 + arow)*H_DIM + k0 + acol,
                    &As[(wm + g*8)*64]);
      #pragma unroll
      for (int g = 0; g < 2; g++)
        gload_lds16(sgut + (size_t)(n0 + wave*16 + g*8 + arow)*H_DIM + k0 + acol,
                    &Bs[(wave*16 + g*8)*64]);
      asm volatile("s_waitcnt vmcnt(0) lgkmcnt(0)" ::: "memory");
      __syncthreads();
      #pragma unroll
      for (int kk = 0; kk < 2; kk++) {
        const int cb = fg + kk*4;
        f16x8 a[4], b[4];
        #pragma unroll
        for (int m = 0; m < 4; m++) {
          const int r = wm + m*16 + fr;
          a[m] = *(const f16x8*)&As[r*64 + ((cb ^ (r & 7)) * 8)];
        }
        #pragma unroll
        for (int n = 0; n < 4; n++) {
          const int r = n*16 + fr;
          b[n] = *(const f16x8*)&Bs[r*64 + ((cb ^ (r & 7)) * 8)];
        }
        #pragma unroll
        for (int n = 0; n < 4; n++)
          #pragma unroll
          for (int m = 0; m < 4; m++)
            acc[m][n] = __builtin_amdgcn_mfma_f32_16x16x32_f16(a[m], b[n], acc[m][n], 0,0,0);
      }
      __syncthreads();
    }
    #pragma unroll
    for (int m = 0; m < 4; m++)
      #pragma unroll
      for (int n = 0; n < 4; n++)
        #pragma unroll
        for (int j = 0; j < 4; j++)
          gu_sh[(size_t)(m0 + wm + m*16 + cr + j) * FF2 + (n0 + n*16 + cc)] = acc[m][n][j];
  }
}

// ---------------- gemm_dn_all: expert down (tile queue, f32 B -> y_exp) + shared down (u16 B -> out) ----------------
__global__ __launch_bounds__(256) void gemm_dn_all_kernel(
    const u16* __restrict__ Aexp, const float* __restrict__ edn, float* __restrict__ y_exp,
    const int* __restrict__ counts, const int* __restrict__ offs,
    const int* __restrict__ tile_e, const int* __restrict__ tile_m0,
    const u16* __restrict__ act_sh, const u16* __restrict__ sdnt, float* __restrict__ out_sh)
{
  __shared__ u16 As[256*64];
  __shared__ u16 Bs[64*64];
  const int z = blockIdx.z;
  const int tid = threadIdx.x, lane = tid & 63, wave = tid >> 6;
  const int n0 = blockIdx.x * 64;
  const int wm = wave * 64;
  const int arow = lane >> 3;
  const int acol = ((lane & 7) ^ arow) * 8;
  const int fr = lane & 15, fg = lane >> 4;
  const int cr = (lane >> 4) * 4, cc = lane & 15;

  if (z < 32) {
    const int e = tile_e[z];
    if (e < 0) return;
    const int m0 = tile_m0[z];
    const int cnt = counts[e];
    const int off = offs[e];
    const u16* A = Aexp + (size_t)off * FFE;
    const float* B = edn + (size_t)e * FFE * H_DIM;
    float* C = y_exp + (size_t)off * H_DIM;
    const int bn  = tid & 63;
    const int bkb = tid >> 6;
    const int bs0 = bn*64 + (((bkb*2)     ^ (bn & 7)) * 8);
    const int bs1 = bn*64 + (((bkb*2 + 1) ^ (bn & 7)) * 8);
    f32x4 acc[4][4] = {};
    for (int k0 = 0; k0 < FFE; k0 += 64) {
      #pragma unroll
      for (int g = 0; g < 8; g++)
        gload_lds16(A + (size_t)(m0 + wm + g*8 + arow)*FFE + k0 + acol,
                    &As[(wm + g*8)*64]);
      {
        const float* gb = B + (size_t)(k0 + bkb*16) * H_DIM + (n0 + bn);
        float f[16];
        #pragma unroll
        for (int j = 0; j < 16; j++) f[j] = gb[(size_t)j * H_DIM];
        u32 pk[8];
        #pragma unroll
        for (int j = 0; j < 8; j++)
          pk[j] = __builtin_bit_cast(u32, __builtin_amdgcn_cvt_pkrtz(f[2*j], f[2*j+1]));
        *(uint4*)&Bs[bs0] = make_uint4(pk[0], pk[1], pk[2], pk[3]);
        *(uint4*)&Bs[bs1] = make_uint4(pk[4], pk[5], pk[6], pk[7]);
      }
      asm volatile("s_waitcnt vmcnt(0) lgkmcnt(0)" ::: "memory");
      __syncthreads();
      #pragma unroll
      for (int kk = 0; kk < 2; kk++) {
        const int cb = fg + kk*4;
        f16x8 a[4], b[4];
        #pragma unroll
        for (int m = 0; m < 4; m++) {
          const int r = wm + m*16 + fr;
          a[m] = *(const f16x8*)&As[r*64 + ((cb ^ (r & 7)) * 8)];
        }
        #pragma unroll
        for (int n = 0; n < 4; n++) {
          const int r = n*16 + fr;
          b[n] = *(const f16x8*)&Bs[r*64 + ((cb ^ (r & 7)) * 8)];
        }
        #pragma unroll
        for (int n = 0; n < 4; n++)
          #pragma unroll
          for (int m = 0; m < 4; m++)
            acc[m][n] = __builtin_amdgcn_mfma_f32_16x16x32_f16(a[m], b[n], acc[m][n], 0,0,0);
      }
      __syncthreads();
    }
    #pragma unroll
    for (int m = 0; m < 4; m++)
      #pragma unroll
      for (int n = 0; n < 4; n++)
        #pragma unroll
        for (int j = 0; j < 4; j++) {
          int r = m0 + wm + m*16 + cr + j;
          if (r < cnt) C[(size_t)r * H_DIM + (n0 + n*16 + cc)] = acc[m][n][j];
        }
  } else {
    const int m0 = (z - 32) * 256;
    f32x4 acc[4][4] = {};
    for (int k0 = 0; k0 < FFE; k0 += 64) {
      #pragma unroll
      for (int g = 0; g < 8; g++)
        gload_lds16(act_sh + (size_t)(m0 + wm + g*8 + arow)*FFE + k0 + acol,
                    &As[(wm + g*8)*64]);
      #pragma unroll
      for (int g = 0; g < 2; g++)
        gload_lds16(sdnt + (size_t)(n0 + wave*16 + g*8 + arow)*FFE + k0 + acol,
                    &Bs[(wave*16 + g*8)*64]);
      asm volatile("s_waitcnt vmcnt(0) lgkmcnt(0)" ::: "memory");
      __syncthreads();
      #pragma unroll
      for (int kk = 0; kk < 2; kk++) {
        const int cb = fg + kk*4;
        f16x8 a[4], b[4];
        #pragma unroll
        for (int m = 0; m < 4; m++) {
          const int r = wm + m*16 + fr;
          a[m] = *(const f16x8*)&As[r*64 + ((cb ^ (r & 7)) * 8)];
        }
        #pragma unroll
        for (int n = 0; n < 4; n++) {
          const int r = n*16 + fr;
          b[n] = *(const f16x8*)&Bs[r*64 + ((cb ^ (r & 7)) * 8)];
        }
        #pragma unroll
        for (int n = 0; n < 4; n++)
          #pragma unroll
          for (int m = 0; m < 4; m++)
            acc[m][n] = __builtin_amdgcn_mfma_f32_16x16x32_f16(a[m], b[n], acc[m][n], 0,0,0);
      }
      __syncthreads();
    }
    #pragma unroll
    for (int m = 0; m < 4; m++)
      #pragma unroll
      for (int n = 0; n < 4; n++)
        #pragma unroll
        for (int j = 0; j < 4; j++)
          out_sh[(size_t)(m0 + wm + m*16 + cr + j) * H_DIM + (n0 + n*16 + cc)] = acc[m][n][j];
  }
}

// ---------------- per-head q/k rmsnorm + rope + v relayout, from fused qkv f32 ----------------
__global__ __launch_bounds__(256) void rope_kernel(
    const float* __restrict__ qkv,
    const float* __restrict__ cosb, const float* __restrict__ sinb,
    const float* __restrict__ qnw, const float* __restrict__ knw,
    u16* __restrict__ qrh, u16* __restrict__ qrl,
    u16* __restrict__ krh, u16* __restrict__ krl,
    u16* __restrict__ vth, u16* __restrict__ vtl)
{
  const int jid = blockIdx.x * 4 + (threadIdx.x >> 6);
  const int lane = threadIdx.x & 63;
  const int t = jid / 24, r = jid - t*24;
  const int b = t >> 10, s = t & (S_LEN - 1);
  const float* row = qkv + (size_t)t * 3072;
  if (r < NHEAD + NKVH) {
    const bool isq = (r < NHEAD);
    const int h = isq ? r : (r - NHEAD);
    const float* x = row + (isq ? h*DHEAD : (2048 + h*DHEAD));
    const float* nw = isq ? qnw : knw;
    float x0 = x[lane], x1 = x[lane + 64];
    float ss = x0*x0 + x1*x1;
    #pragma unroll
    for (int d = 1; d < 64; d <<= 1) ss += __shfl_xor(ss, d, 64);
    float rinv = rsqrtf(ss * (1.0f/DHEAD) + EPSF);
    float n0 = x0*rinv*nw[lane], n1 = x1*rinv*nw[lane + 64];
    float o0 = n0*cosb[s*DHEAD + lane]      - n1*sinb[s*DHEAD + lane];
    float o1 = n1*cosb[s*DHEAD + lane + 64] + n0*sinb[s*DHEAD + lane + 64];
    size_t base = isq ? ((size_t)(b*NHEAD + h)*S_LEN + s)*DHEAD
                      : ((size_t)(b*NKVH + h)*S_LEN + s)*DHEAD;
    u16* dh = isq ? qrh : krh;
    u16* dl = isq ? qrl : krl;
    u16 hh, ll;
    split2(o0, hh, ll); dh[base + lane]      = hh; dl[base + lane]      = ll;
    split2(o1, hh, ll); dh[base + lane + 64] = hh; dl[base + lane + 64] = ll;
  } else {
    const int h = r - NHEAD - NKVH;
    const float* x = row + 2560 + h*DHEAD;
    size_t base = (size_t)(b*NKVH + h)*DHEAD*S_LEN + s;
    u16 hh, ll;
    split2(x[lane], hh, ll);
    vth[base + (size_t)lane*S_LEN] = hh; vtl[base + (size_t)lane*S_LEN] = ll;
    split2(x[lane + 64], hh, ll);
    vth[base + (size_t)(lane + 64)*S_LEN] = hh; vtl[base + (size_t)(lane + 64)*S_LEN] = ll;
  }
}

// ---------------- attn_mix: flash attention (z<2) + tsplit wo/sgu/sdn (z=2,3,4) ----------------
// grid (44,32,5). attn: bx<8, h<16, b=z. tsplit blocks co-reside with attn blocks (16.6KB vs 80KB LDS).
__global__ __launch_bounds__(256) void attn_mix_kernel(
    const u16* __restrict__ qrh, const u16* __restrict__ qrl,
    const u16* __restrict__ krh, const u16* __restrict__ krl,
    const u16* __restrict__ vth, const u16* __restrict__ vtl,
    u16* __restrict__ oh, u16* __restrict__ ol,
    const float* __restrict__ wo, const float* __restrict__ sgu, const float* __restrict__ sdn,
    u16* __restrict__ woh, u16* __restrict__ wol,
    u16* __restrict__ sgut, u16* __restrict__ sdnt)
{
  __shared__ __align__(16) char smem[81920];
  const int z = blockIdx.z;
  if (z >= 2) {
    const float* in; int ldn; u16* outh; u16* outl; int ldk, nx, ny; bool dual;
    switch (z) {
      case 2:  in=wo;  ldn=2048; outh=woh;  outl=wol;     ldk=2048; nx=32; ny=32; dual=true;  break;
      case 3:  in=sgu; ldn=2816; outh=sgut; outl=nullptr; ldk=2048; nx=44; ny=32; dual=false; break;
      default: in=sdn; ldn=2048; outh=sdnt; outl=nullptr; ldk=1408; nx=32; ny=22; dual=false; break;
    }
    if ((int)blockIdx.x >= nx || (int)blockIdx.y >= ny) return;
    tsplit_body(in, ldn, outh, outl, ldk, dual, smem);
    return;
  }
  if ((int)blockIdx.x >= 8 || (int)blockIdx.y >= NHEAD) return;
  u16* Kh = (u16*)smem;
  u16* Kl = (u16*)(smem + 16384);
  u16* Vh = (u16*)(smem + 32768);
  u16* Vl = (u16*)(smem + 49152);
  u16* Ph = (u16*)(smem + 65536);
  u16* Pl = (u16*)(smem + 73728);
  const int bx = blockIdx.x, h = blockIdx.y, b = z;
  const int hkv = h >> 2;
  const int lane = threadIdx.x & 63, wave = threadIdx.x >> 6;
  const int fr = lane & 15, fg = lane >> 4;
  const u16* qbh = qrh + ((size_t)(b*NHEAD + h)*S_LEN)*DHEAD;
  const u16* qbl = qrl + ((size_t)(b*NHEAD + h)*S_LEN)*DHEAD;
  const u16* kbh = krh + ((size_t)(b*NKVH + hkv)*S_LEN)*DHEAD;
  const u16* kbl = krl + ((size_t)(b*NKVH + hkv)*S_LEN)*DHEAD;
  const u16* vbh = vth + ((size_t)(b*NKVH + hkv)*DHEAD)*S_LEN;
  const u16* vbl = vtl + ((size_t)(b*NKVH + hkv)*DHEAD)*S_LEN;
  const float scl = 0.08838834764831845f;

  for (int it = 0; it < 2; it++) {
    const int qt = it ? (15 - bx) : bx;
    const int q0 = qt * 64;
    f16x8 aqh[4], aql[4];
    {
      const size_t qrow = (size_t)(q0 + wave*16 + fr)*DHEAD;
      #pragma unroll
      for (int kk = 0; kk < 4; kk++) {
        aqh[kk] = *(const f16x8*)&qbh[qrow + kk*32 + fg*8];
        aql[kk] = *(const f16x8*)&qbl[qrow + kk*32 + fg*8];
      }
    }
    f32x4 o0[8] = {}, o1[8] = {};
    float mrow[4] = {-1e30f,-1e30f,-1e30f,-1e30f};
    float lrow[4] = {0.f,0.f,0.f,0.f};
    for (int jt = 0; jt <= qt; jt++) {
      const int j0 = jt * 64;
      #pragma unroll
      for (int p = 0; p < 4; p++) {
        const int ck = p*4 + wave;
        gload_lds16(kbh + (size_t)(j0 + ck*4 + (lane>>4))*DHEAD + (lane&15)*8, &Kh[ck*512]);
        gload_lds16(kbl + (size_t)(j0 + ck*4 + (lane>>4))*DHEAD + (lane&15)*8, &Kl[ck*512]);
        gload_lds16(vbh + (size_t)(ck*8 + (lane>>3))*S_LEN + j0 + (lane&7)*8, &Vh[ck*512]);
        gload_lds16(vbl + (size_t)(ck*8 + (lane>>3))*S_LEN + j0 + (lane&7)*8, &Vl[ck*512]);
      }
      __syncthreads();
      f32x4 s0[4] = {}, s1[4] = {};
      #pragma unroll
      for (int kk = 0; kk < 4; kk++) {
        const int ko = kk*32 + fg*8;
        #pragma unroll
        for (int n = 0; n < 4; n++) {
          f16x8 bh_ = *(const f16x8*)&Kh[(n*16 + fr)*128 + ko];
          f16x8 bl_ = *(const f16x8*)&Kl[(n*16 + fr)*128 + ko];
          s0[n] = __builtin_amdgcn_mfma_f32_16x16x32_f16(aqh[kk], bh_, s0[n], 0,0,0);
          s1[n] = __builtin_amdgcn_mfma_f32_16x16x32_f16(aqh[kk], bl_, s1[n], 0,0,0);
          s1[n] = __builtin_amdgcn_mfma_f32_16x16x32_f16(aql[kk], bh_, s1[n], 0,0,0);
        }
      }
      const int rb = q0 + wave*16 + fg*4;
      float pv[4][4];
      #pragma unroll
      for (int n = 0; n < 4; n++)
        #pragma unroll
        for (int j = 0; j < 4; j++) {
          float v = (s0[n][j] + s1[n][j]*(1.0f/2048.0f)) * scl;
          if (j0 + n*16 + fr > rb + j) v = -1e30f;
          pv[n][j] = v;
        }
      float alpha[4];
      #pragma unroll
      for (int j = 0; j < 4; j++) {
        float mx = fmaxf(fmaxf(pv[0][j], pv[1][j]), fmaxf(pv[2][j], pv[3][j]));
        #pragma unroll
        for (int d = 1; d < 16; d <<= 1) mx = fmaxf(mx, __shfl_xor(mx, d, 64));
        float mnew = fmaxf(mrow[j], mx);
        alpha[j] = __expf(mrow[j] - mnew);
        mrow[j] = mnew;
      }
      float rsum[4] = {0.f,0.f,0.f,0.f};
      #pragma unroll
      for (int n = 0; n < 4; n++)
        #pragma unroll
        for (int j = 0; j < 4; j++) {
          float p = __expf(pv[n][j] - mrow[j]);
          pv[n][j] = p;
          rsum[j] += p;
        }
      #pragma unroll
      for (int j = 0; j < 4; j++) {
        #pragma unroll
        for (int d = 1; d < 16; d <<= 1) rsum[j] += __shfl_xor(rsum[j], d, 64);
        lrow[j] = lrow[j]*alpha[j] + rsum[j];
      }
      #pragma unroll
      for (int n2 = 0; n2 < 8; n2++)
        #pragma unroll
        for (int j = 0; j < 4; j++) { o0[n2][j] *= alpha[j]; o1[n2][j] *= alpha[j]; }
      #pragma unroll
      for (int n = 0; n < 4; n++)
        #pragma unroll
        for (int j = 0; j < 4; j++) {
          u16 hh, ll; split2(pv[n][j], hh, ll);
          Ph[wave*1024 + (fg*4 + j)*64 + n*16 + fr] = hh;
          Pl[wave*1024 + (fg*4 + j)*64 + n*16 + fr] = ll;
        }
      __syncthreads();
      #pragma unroll
      for (int kk = 0; kk < 2; kk++) {
        const int ko = kk*32 + fg*8;
        f16x8 ah_ = *(const f16x8*)&Ph[wave*1024 + fr*64 + ko];
        f16x8 al_ = *(const f16x8*)&Pl[wave*1024 + fr*64 + ko];
        #pragma unroll
        for (int n2 = 0; n2 < 8; n2++) {
          f16x8 vh_ = *(const f16x8*)&Vh[(n2*16 + fr)*64 + ko];
          f16x8 vl_ = *(const f16x8*)&Vl[(n2*16 + fr)*64 + ko];
          o0[n2] = __builtin_amdgcn_mfma_f32_16x16x32_f16(ah_, vh_, o0[n2], 0,0,0);
          o1[n2] = __builtin_amdgcn_mfma_f32_16x16x32_f16(ah_, vl_, o1[n2], 0,0,0);
          o1[n2] = __builtin_amdgcn_mfma_f32_16x16x32_f16(al_, vh_, o1[n2], 0,0,0);
        }
      }
      __syncthreads();
    }
    float inv[4];
    #pragma unroll
    for (int j = 0; j < 4; j++) inv[j] = 1.0f / lrow[j];
    #pragma unroll
    for (int n2 = 0; n2 < 8; n2++)
      #pragma unroll
      for (int j = 0; j < 4; j++) {
        int s = q0 + wave*16 + fg*4 + j;
        size_t idx = ((size_t)(b*S_LEN + s))*H_DIM + h*DHEAD + n2*16 + fr;
        float val = (o0[n2][j] + o1[n2][j]*(1.0f/2048.0f)) * inv[j];
        u16 hh, ll; split2(val, hh, ll);
        oh[idx] = hh; ol[idx] = ll;
      }
  }
}

// ---------------- router: f32 rmsnorm + logits + top-2 ----------------
__global__ __launch_bounds__(64) void router_kernel(
    const float* __restrict__ resid, const float* __restrict__ ln2w,
    const float* __restrict__ gw, int* __restrict__ ids, float* __restrict__ wts,
    int* __restrict__ counts)
{
  const int t = blockIdx.x, lane = threadIdx.x;
  const float* x = resid + (size_t)t * H_DIM;
  float xv[32];
  float ss = 0.f;
  #pragma unroll
  for (int p = 0; p < 8; p++) {
    float4 v  = *(const float4*)&x[p*256 + lane*4];
    float4 lw = *(const float4*)&ln2w[p*256 + lane*4];
    ss += v.x*v.x + v.y*v.y + v.z*v.z + v.w*v.w;
    xv[p*4+0] = v.x*lw.x; xv[p*4+1] = v.y*lw.y; xv[p*4+2] = v.z*lw.z; xv[p*4+3] = v.w*lw.w;
  }
  #pragma unroll
  for (int d = 1; d < 64; d <<= 1) ss += __shfl_xor(ss, d, 64);
  const float rinv = rsqrtf(ss * (1.0f/H_DIM) + EPSF);
  float lg[NEXP];
  #pragma unroll
  for (int e = 0; e < NEXP; e++) {
    const float* g = gw + (size_t)e * H_DIM;
    float dacc = 0.f;
    #pragma unroll
    for (int p = 0; p < 8; p++) {
      float4 gv = *(const float4*)&g[p*256 + lane*4];
      dacc += xv[p*4+0]*gv.x + xv[p*4+1]*gv.y + xv[p*4+2]*gv.z + xv[p*4+3]*gv.w;
    }
    #pragma unroll
    for (int d = 1; d < 64; d <<= 1) dacc += __shfl_xor(dacc, d, 64);
    lg[e] = dacc * rinv;
  }
  if (lane == 0) {
    int i0 = 0; float b0 = lg[0];
    #pragma unroll
    for (int e = 1; e < NEXP; e++) if (lg[e] > b0) { b0 = lg[e]; i0 = e; }
    int i1 = -1; float b1 = -3e38f;
    #pragma unroll
    for (int e = 0; e < NEXP; e++) if (e != i0 && lg[e] > b1) { b1 = lg[e]; i1 = e; }
    float rr = __expf(b1 - b0);
    float w0 = 1.0f / (1.0f + rr);
    ids[t*2] = i0; ids[t*2+1] = i1;
    wts[t*2] = w0; wts[t*2+1] = rr * w0;
    atomicAdd(&counts[i0], 1);
    atomicAdd(&counts[i1], 1);
  }
}

__global__ void scan_kernel(const int* __restrict__ counts, int* __restrict__ offs,
                            int* __restrict__ cursor,
                            int* __restrict__ tile_e, int* __restrict__ tile_m0)
{
  if (threadIdx.x == 0) {
    int s = 0, nt = 0;
    for (int e = 0; e < NEXP; e++) {
      offs[e] = s; cursor[e] = 0;
      int c = counts[e];
      for (int m0 = 0; m0 < c; m0 += 256) { tile_e[nt] = e; tile_m0[nt] = m0; nt++; }
      s += c;
    }
    for (; nt < 32; nt++) { tile_e[nt] = -1; tile_m0[nt] = 0; }
  }
}

__global__ __launch_bounds__(256) void scatter_kernel(
    const int* __restrict__ ids, const int* __restrict__ offs,
    int* __restrict__ cursor, int* __restrict__ list, int* __restrict__ pos)
{
  int t = blockIdx.x * 256 + threadIdx.x;
  if (t < T_TOK) {
    for (int kk = 0; kk < 2; kk++) {
      int e = ids[t*2 + kk];
      int p = atomicAdd(&cursor[e], 1);
      int i = offs[e] + p;
      list[i] = t;
      pos[t*2 + kk] = i;
    }
  }
}

// ---------------- silu_all: expert rows (0..4095) + shared rows (4096..6143) ----------------
__global__ __launch_bounds__(256) void silu_all_kernel(
    const float* __restrict__ gu_exp, u16* __restrict__ act_ex,
    const float* __restrict__ gu_sh,  u16* __restrict__ act_sh)
{
  const int rr = blockIdx.x;
  const float* g;
  u16* o;
  if (rr < 2*T_TOK) { g = gu_exp + (size_t)rr * FF2;          o = act_ex + (size_t)rr * FFE; }
  else              { g = gu_sh  + (size_t)(rr - 2*T_TOK) * FF2; o = act_sh + (size_t)(rr - 2*T_TOK) * FFE; }
  for (int c = threadIdx.x*4; c < FFE; c += 1024) {
    float4 gv = *(const float4*)&g[c];
    float4 uv = *(const float4*)&g[c + FFE];
    float s0 = gv.x / (1.0f + __expf(-gv.x)) * uv.x;
    float s1 = gv.y / (1.0f + __expf(-gv.y)) * uv.y;
    float s2 = gv.z / (1.0f + __expf(-gv.z)) * uv.z;
    float s3 = gv.w / (1.0f + __expf(-gv.w)) * uv.w;
    u32 lo = (u32)f2h(s0) | ((u32)f2h(s1) << 16);
    u32 hi = (u32)f2h(s2) | ((u32)f2h(s3) << 16);
    *(uint2*)&o[c] = make_uint2(lo, hi);
  }
}

// out = out(shared) + w0*y[p0] + w1*y[p1]   (in-place RMW on d_out)
__global__ __launch_bounds__(256) void combine_kernel(
    const float* __restrict__ y,
    const int* __restrict__ pos, const float* __restrict__ wts,
    float* __restrict__ out)
{
  const int t = blockIdx.x;
  const int p0 = pos[t*2], p1 = pos[t*2+1];
  const float w0 = wts[t*2] * RSF_C, w1 = wts[t*2+1] * RSF_C;
  const int c = threadIdx.x * 8;
  #pragma unroll
  for (int q = 0; q < 2; q++) {
    const int cc = c + q*4;
    float4 s  = *(const float4*)&out[(size_t)t*H_DIM + cc];
    float4 a  = *(const float4*)&y[(size_t)p0*H_DIM + cc];
    float4 bb = *(const float4*)&y[(size_t)p1*H_DIM + cc];
    float4 r;
    r.x = s.x + w0*a.x + w1*bb.x;
    r.y = s.y + w0*a.y + w1*bb.y;
    r.z = s.z + w0*a.z + w1*bb.z;
    r.w = s.w + w0*a.w + w1*bb.w;
    *(float4*)&out[(size_t)t*H_DIM + cc] = r;
  }
}

extern "C" void kernel_launch(void* const* d_in, const int* in_sizes, int n_in,
                              void* d_out, int out_size, void* d_ws, size_t ws_size,
                              hipStream_t stream)
{
  (void)in_sizes; (void)n_in; (void)out_size;
  const float* hidden = (const float*)d_in[0];
  const float* cosb   = (const float*)d_in[1];
  const float* sinb   = (const float*)d_in[2];
  const float* ln1w   = (const float*)d_in[3];
  const float* ln2w   = (const float*)d_in[4];
  const float* qnw    = (const float*)d_in[5];
  const float* knw    = (const float*)d_in[6];
  const float* wq     = (const float*)d_in[7];
  const float* wk     = (const float*)d_in[8];
  const float* wv     = (const float*)d_in[9];
  const float* wo     = (const float*)d_in[10];
  const float* gw     = (const float*)d_in[11];
  const float* egu    = (const float*)d_in[12];
  const float* edn    = (const float*)d_in[13];
  const float* sgu    = (const float*)d_in[14];
  const float* sdn    = (const float*)d_in[15];
  float* out_hidden = (float*)d_out;
  float* resid = (float*)d_out + (size_t)T_TOK * H_DIM;

  char* ws = (char*)d_ws;
  // ---- phase A (pre-router) ----
  constexpr size_t OFF_XH    = 0;
  constexpr size_t OFF_XL    = 8388608;
  constexpr size_t OFF_WQKVH = 16777216;
  constexpr size_t OFF_WQKVL = 29360128;
  constexpr size_t OFF_WOH   = 41943040;
  constexpr size_t OFF_WOL   = 50331648;
  constexpr size_t OFF_QKV   = 58720256;   // 25,165,824 f32 [2048][3072]
  constexpr size_t OFF_QRH = 16777216, OFF_QRL = 25165824;
  constexpr size_t OFF_KRH = 33554432, OFF_KRL = 35651584;
  constexpr size_t OFF_VTH = 37748736, OFF_VTL = 39845888;
  constexpr size_t OFF_OH = 58720256, OFF_OL = 67108864;
  // ---- phase B (post-router) ----
  constexpr size_t OFF_GUE = 0;            // gu_exp 46,137,344 ; later y_exp 33,554,432
  constexpr size_t OFF_TOK = 63963136;     // 8,388,608
  constexpr size_t OFF_ACE = 72351744;     // act_ex (4096+256)x1408x2 = 12,255,232
  constexpr size_t OFF_GUS = 84606976;     // 23,068,672
  constexpr size_t OFF_ACS = 107675648;    // 5,767,168
  constexpr size_t OFF_SGUT= 113442816;    // 11,534,336
  constexpr size_t OFF_SDNT= 124977152;    // 5,767,168
  constexpr size_t OFF_IDS = 130744320;
  constexpr size_t OFF_WTS = OFF_IDS + 16384;
  constexpr size_t OFF_POS = OFF_WTS + 16384;
  constexpr size_t OFF_LST = OFF_POS + 16384;
  constexpr size_t OFF_CNT = OFF_LST + 16384;
  constexpr size_t OFF_OFS = OFF_CNT + 64;
  constexpr size_t OFF_CUR = OFF_OFS + 64;
  constexpr size_t OFF_TE  = OFF_CUR + 64;
  constexpr size_t OFF_TM  = OFF_TE + 128;
  constexpr size_t WS_NEED = OFF_TM + 128;
  if (ws_size < WS_NEED) return;

  u16* xh     = (u16*)(ws + OFF_XH);
  u16* xl     = (u16*)(ws + OFF_XL);
  u16* wqkvh  = (u16*)(ws + OFF_WQKVH);
  u16* wqkvl  = (u16*)(ws + OFF_WQKVL);
  u16* woh    = (u16*)(ws + OFF_WOH);
  u16* wol    = (u16*)(ws + OFF_WOL);
  float* qkv  = (float*)(ws + OFF_QKV);
  u16* q_rh = (u16*)(ws + OFF_QRH);
  u16* q_rl = (u16*)(ws + OFF_QRL);
  u16* k_rh = (u16*)(ws + OFF_KRH);
  u16* k_rl = (u16*)(ws + OFF_KRL);
  u16* v_th = (u16*)(ws + OFF_VTH);
  u16* v_tl = (u16*)(ws + OFF_VTL);
  u16* o_h  = (u16*)(ws + OFF_OH);
  u16* o_l  = (u16*)(ws + OFF_OL);
  float* gu_exp = (float*)(ws + OFF_GUE);
  float* y_exp  = (float*)(ws + OFF_GUE);
  u16* tok      = (u16*)(ws + OFF_TOK);
  u16* act_ex   = (u16*)(ws + OFF_ACE);
  float* gu_sh  = (float*)(ws + OFF_GUS);
  u16* act_sh   = (u16*)(ws + OFF_ACS);
  u16* sgut     = (u16*)(ws + OFF_SGUT);
  u16* sdnt     = (u16*)(ws + OFF_SDNT);
  int* ids    = (int*)(ws + OFF_IDS);
  float* wts  = (float*)(ws + OFF_WTS);
  int* pos    = (int*)(ws + OFF_POS);
  int* list   = (int*)(ws + OFF_LST);
  int* counts = (int*)(ws + OFF_CNT);
  int* offs   = (int*)(ws + OFF_OFS);
  int* cursor = (int*)(ws + OFF_CUR);
  int* tile_e = (int*)(ws + OFF_TE);
  int* tile_m0= (int*)(ws + OFF_TM);

  hipMemsetAsync(counts, 0, 64, stream);

  // ---- prep: only wq/wk/wv transpose (needed before qkv gemm) ----
  tsplit_all_kernel<<<dim3(32,32,3), 256, 0, stream>>>(wq, wk, wv, wqkvh, wqkvl);

  // ---- pre-router chain (f16 hi/lo precision) ----
  rmsnorm_kernel<<<T_TOK, 256, 0, stream>>>(hidden, ln1w, xh, xl);
  gemm3b_kernel<<<dim3(24,16), 256, 0, stream>>>(xh, xl, H_DIM, wqkvh, wqkvl, 2048, qkv, 3072, nullptr, H_DIM);
  rope_kernel<<<(T_TOK*24)/4, 256, 0, stream>>>(qkv, cosb, sinb, qnw, knw,
                                                q_rh, q_rl, k_rh, k_rl, v_th, v_tl);
  // ---- attention + overlapped wo/sgu/sdn transpose (z-demux) ----
  attn_mix_kernel<<<dim3(44,32,5), 256, 0, stream>>>(q_rh, q_rl, k_rh, k_rl, v_th, v_tl, o_h, o_l,
                                                     wo, sgu, sdn, woh, wol, sgut, sdnt);
  gemm3b_kernel<<<dim3(16,16), 256, 0, stream>>>(o_h, o_l, H_DIM, woh, wol, 2048, resid, H_DIM, hidden, H_DIM);

  // ---- router ----
  rmsnorm_kernel<<<T_TOK, 256, 0, stream>>>(resid, ln2w, tok, nullptr);
  router_kernel<<<T_TOK, 64, 0, stream>>>(resid, ln2w, gw, ids, wts, counts);
  scan_kernel<<<1, 64, 0, stream>>>(counts, offs, cursor, tile_e, tile_m0);
  scatter_kernel<<<8, 256, 0, stream>>>(ids, offs, cursor, list, pos);

  // ---- MoE: merged up (indirect A from tok via list -- no gather), merged silu, merged down, combine ----
  gemm_up_all_kernel<<<dim3(44,1,40), 256, 0, stream>>>(list, egu, gu_exp,
                                                        counts, offs, tile_e, tile_m0,
                                                        tok, sgut, gu_sh);
  silu_all_kernel<<<3*T_TOK, 256, 0, stream>>>(gu_exp, act_ex, gu_sh, act_sh);
  gemm_dn_all_kernel<<<dim3(32,1,40), 256, 0, stream>>>(act_ex, edn, y_exp,
                                                        counts, offs, tile_e, tile_m0,
                                                        act_sh, sdnt, out_hidden);
  combine_kernel<<<T_TOK, 256, 0, stream>>>(y_exp, pos, wts, out_hidden);
}

// Round 23
// 736.261 us; speedup vs baseline: 1.1036x; 1.1036x over previous
//
#include <hip/hip_runtime.h>
#include <stdint.h>

typedef unsigned short u16;
typedef unsigned int   u32;
typedef __attribute__((ext_vector_type(4))) float     f32x4;
typedef __attribute__((ext_vector_type(8))) _Float16  f16x8;

#define S_LEN 1024
#define NB    2
#define H_DIM 2048
#define T_TOK 2048
#define NHEAD 16
#define NKVH  4
#define DHEAD 128
#define NEXP  16
#define FFE   1408
#define FF2   2816
#define EPSF  1e-5f
#define RSF_C 1.0f

// ---- f32 <-> f16 helpers (scaled hi/lo split: x ~= hi + lo/2048) ----
__device__ __forceinline__ u16 f2h(float f){
  _Float16 h = (_Float16)f;
  return __builtin_bit_cast(unsigned short, h);
}
__device__ __forceinline__ void split2(float f, u16& hi, u16& lo){
  _Float16 h = (_Float16)f;
  hi = __builtin_bit_cast(unsigned short, h);
  _Float16 l = (_Float16)((f - (float)h) * 2048.0f);
  lo = __builtin_bit_cast(unsigned short, l);
}
__device__ __forceinline__ void gload_lds16(const void* g, void* l){
  __builtin_amdgcn_global_load_lds((const __attribute__((address_space(1))) void*)g,
                                   (__attribute__((address_space(3))) void*)l, 16, 0, 0);
}
__device__ __forceinline__ uint4 pack8(const u16* p){
  return make_uint4((u32)p[0] | ((u32)p[1]<<16), (u32)p[2] | ((u32)p[3]<<16),
                    (u32)p[4] | ((u32)p[5]<<16), (u32)p[6] | ((u32)p[7]<<16));
}

// ---------------- tsplit_all: all six weight transpose/split jobs in one launch ----------------
// z: 0=wq 1=wk 2=wv 3=wo (dual) 4=sgu 5=sdn (single). grid (44,32,6); oversized blocks exit early.
__global__ __launch_bounds__(256) void tsplit_all_kernel(
    const float* __restrict__ wq, const float* __restrict__ wk,
    const float* __restrict__ wv, const float* __restrict__ wo,
    const float* __restrict__ sgu, const float* __restrict__ sdn,
    u16* __restrict__ wqkvh, u16* __restrict__ wqkvl,
    u16* __restrict__ woh,  u16* __restrict__ wol,
    u16* __restrict__ sgut, u16* __restrict__ sdnt)
{
  const int z = blockIdx.z;
  const float* in; int ldn; u16* outh; u16* outl; int ldk, nx, ny; bool dual;
  switch (z) {
    case 0:  in=wq;  ldn=2048; outh=wqkvh;              outl=wqkvl;              ldk=2048; nx=32; ny=32; dual=true;  break;
    case 1:  in=wk;  ldn=512;  outh=wqkvh+2048*2048;    outl=wqkvl+2048*2048;    ldk=2048; nx=8;  ny=32; dual=true;  break;
    case 2:  in=wv;  ldn=512;  outh=wqkvh+2560*2048;    outl=wqkvl+2560*2048;    ldk=2048; nx=8;  ny=32; dual=true;  break;
    case 3:  in=wo;  ldn=2048; outh=woh;                outl=wol;                ldk=2048; nx=32; ny=32; dual=true;  break;
    case 4:  in=sgu; ldn=2816; outh=sgut;               outl=nullptr;            ldk=2048; nx=44; ny=32; dual=false; break;
    default: in=sdn; ldn=2048; outh=sdnt;               outl=nullptr;            ldk=1408; nx=32; ny=22; dual=false; break;
  }
  if ((int)blockIdx.x >= nx || (int)blockIdx.y >= ny) return;
  __shared__ float tile[64][65];
  const int n0 = blockIdx.x * 64, k0 = blockIdx.y * 64;
  const int tid = threadIdx.x;
  const int tr = tid >> 4, tc = (tid & 15) * 4;
  #pragma unroll
  for (int i = 0; i < 4; i++) {
    float4 v = *(const float4*)&in[(size_t)(k0 + tr + i*16) * ldn + (n0 + tc)];
    tile[tr + i*16][tc+0] = v.x; tile[tr + i*16][tc+1] = v.y;
    tile[tr + i*16][tc+2] = v.z; tile[tr + i*16][tc+3] = v.w;
  }
  __syncthreads();
  const int n = tid >> 2, kg = (tid & 3) * 16;
  u16 hb[16], lb[16];
  #pragma unroll
  for (int j = 0; j < 16; j++) {
    float f = tile[kg + j][n];
    if (dual) split2(f, hb[j], lb[j]); else hb[j] = f2h(f);
  }
  u16* dh = &outh[(size_t)(n0 + n) * ldk + k0 + kg];
  *(uint4*)dh       = pack8(hb);
  *(uint4*)(dh + 8) = pack8(hb + 8);
  if (dual) {
    u16* dl = &outl[(size_t)(n0 + n) * ldk + k0 + kg];
    *(uint4*)dl       = pack8(lb);
    *(uint4*)(dl + 8) = pack8(lb + 8);
  }
}

// ---------------- RMSNorm: f32 in -> f16 hi (+optional scaled lo) ----------------
__global__ __launch_bounds__(256) void rmsnorm_kernel(
    const float* __restrict__ in, const float* __restrict__ w,
    u16* __restrict__ outh, u16* __restrict__ outl)
{
  __shared__ float red[4];
  const int t = blockIdx.x, tid = threadIdx.x;
  const int lane = tid & 63, wave = tid >> 6;
  const float* x = in + (size_t)t * H_DIM;
  const int c = tid * 8;
  float4 v0 = *(const float4*)&x[c];
  float4 v1 = *(const float4*)&x[c + 4];
  float ss = v0.x*v0.x + v0.y*v0.y + v0.z*v0.z + v0.w*v0.w
           + v1.x*v1.x + v1.y*v1.y + v1.z*v1.z + v1.w*v1.w;
  #pragma unroll
  for (int d = 1; d < 64; d <<= 1) ss += __shfl_xor(ss, d, 64);
  if (lane == 0) red[wave] = ss;
  __syncthreads();
  float rinv = rsqrtf((red[0]+red[1]+red[2]+red[3]) * (1.0f/H_DIM) + EPSF);
  float4 w0 = *(const float4*)&w[c];
  float4 w1 = *(const float4*)&w[c + 4];
  float vals[8] = { v0.x*rinv*w0.x, v0.y*rinv*w0.y, v0.z*rinv*w0.z, v0.w*rinv*w0.w,
                    v1.x*rinv*w1.x, v1.y*rinv*w1.y, v1.z*rinv*w1.z, v1.w*rinv*w1.w };
  u16 hb[8], lb[8];
  #pragma unroll
  for (int j = 0; j < 8; j++) split2(vals[j], hb[j], lb[j]);
  *(uint4*)&outh[(size_t)t * H_DIM + c] = pack8(hb);
  if (outl) *(uint4*)&outl[(size_t)t * H_DIM + c] = pack8(lb);
}

// ---------------- gemm3b: C(f32) = (Ah+Al/2048) @ (Bh+Bl/2048)^T; BK=64, swizzled LDS ----------------
__global__ __launch_bounds__(256) void gemm3b_kernel(
    const u16* __restrict__ Ah, const u16* __restrict__ Al, int lda,
    const u16* __restrict__ Bh, const u16* __restrict__ Bl, int ldb,
    float* __restrict__ C, int ldc,
    const float* __restrict__ addsrc, int K)
{
  __shared__ u16 Ash[128*64], Asl[128*64];
  __shared__ u16 Bsh[128*64], Bsl[128*64];
  const int tid = threadIdx.x, lane = tid & 63, wave = tid >> 6;
  const int m0 = blockIdx.y * 128, n0 = blockIdx.x * 128;
  const int wm = (wave >> 1) * 64, wn = (wave & 1) * 64;
  const int arow = lane >> 3;
  const int acol = ((lane & 7) ^ arow) * 8;
  f32x4 acc0[4][4] = {}, acc1[4][4] = {};
  for (int k0 = 0; k0 < K; k0 += 64) {
    #pragma unroll
    for (int g = 0; g < 4; g++) {
      const int rb = wave*32 + g*8;
      gload_lds16(Ah + (size_t)(m0 + rb + arow)*lda + k0 + acol, &Ash[rb*64]);
      gload_lds16(Al + (size_t)(m0 + rb + arow)*lda + k0 + acol, &Asl[rb*64]);
      gload_lds16(Bh + (size_t)(n0 + rb + arow)*ldb + k0 + acol, &Bsh[rb*64]);
      gload_lds16(Bl + (size_t)(n0 + rb + arow)*ldb + k0 + acol, &Bsl[rb*64]);
    }
    asm volatile("s_waitcnt vmcnt(0) lgkmcnt(0)" ::: "memory");
    __syncthreads();
    const int fr = lane & 15, fg = lane >> 4;
    #pragma unroll
    for (int kk = 0; kk < 2; kk++) {
      const int cb = fg + kk*4;
      f16x8 ah[4], al[4];
      #pragma unroll
      for (int m = 0; m < 4; m++) {
        const int r = wm + m*16 + fr;
        const int s = (cb ^ (r & 7)) * 8;
        ah[m] = *(const f16x8*)&Ash[r*64 + s];
        al[m] = *(const f16x8*)&Asl[r*64 + s];
      }
      #pragma unroll
      for (int n = 0; n < 4; n++) {
        const int r = wn + n*16 + fr;
        const int s = (cb ^ (r & 7)) * 8;
        f16x8 bh_ = *(const f16x8*)&Bsh[r*64 + s];
        f16x8 bl_ = *(const f16x8*)&Bsl[r*64 + s];
        #pragma unroll
        for (int m = 0; m < 4; m++) {
          acc0[m][n] = __builtin_amdgcn_mfma_f32_16x16x32_f16(ah[m], bh_, acc0[m][n], 0,0,0);
          acc1[m][n] = __builtin_amdgcn_mfma_f32_16x16x32_f16(ah[m], bl_, acc1[m][n], 0,0,0);
          acc1[m][n] = __builtin_amdgcn_mfma_f32_16x16x32_f16(al[m], bh_, acc1[m][n], 0,0,0);
        }
      }
    }
    __syncthreads();
  }
  const int cr = (lane >> 4) * 4, cc = lane & 15;
  #pragma unroll
  for (int m = 0; m < 4; m++)
    #pragma unroll
    for (int n = 0; n < 4; n++)
      #pragma unroll
      for (int j = 0; j < 4; j++) {
        int r = m0 + wm + m*16 + cr + j;
        size_t idx = (size_t)r * ldc + (n0 + wn + n*16 + cc);
        float v = acc0[m][n][j] + acc1[m][n][j] * (1.0f/2048.0f);
        if (addsrc) v += addsrc[idx];
        C[idx] = v;
      }
}

// ---------------- gemm_up_all: expert up (tile queue, indirect A via list, f32 B) + shared up (dense, u16 B) ----------------
// grid (44, 1, 40): z<32 -> expert tile z; z>=32 -> shared m-tile (z-32). M=256 x N=64, BK=64.
__global__ __launch_bounds__(256) void gemm_up_all_kernel(
    const int* __restrict__ list, const float* __restrict__ egu, float* __restrict__ gu_exp,
    const int* __restrict__ counts, const int* __restrict__ offs,
    const int* __restrict__ tile_e, const int* __restrict__ tile_m0,
    const u16* __restrict__ tok, const u16* __restrict__ sgut, float* __restrict__ gu_sh)
{
  __shared__ u16 As[256*64];
  __shared__ u16 Bs[64*64];
  const int z = blockIdx.z;
  const int tid = threadIdx.x, lane = tid & 63, wave = tid >> 6;
  const int n0 = blockIdx.x * 64;
  const int wm = wave * 64;
  const int arow = lane >> 3;
  const int acol = ((lane & 7) ^ arow) * 8;
  const int fr = lane & 15, fg = lane >> 4;
  const int cr = (lane >> 4) * 4, cc = lane & 15;

  if (z < 32) {
    const int e = tile_e[z];
    if (e < 0) return;
    const int m0 = tile_m0[z];
    const int cnt = counts[e];
    const int off = offs[e];
    const float* B = egu + (size_t)e * H_DIM * FF2;
    float* C = gu_exp + (size_t)off * FF2;
    const u16* arp[8];
    #pragma unroll
    for (int g = 0; g < 8; g++) {
      int idx = off + m0 + wm + g*8 + arow;
      if (idx > 2*T_TOK - 1) idx = 2*T_TOK - 1;
      arp[g] = tok + (size_t)list[idx] * H_DIM + acol;
    }
    const int bn  = tid & 63;
    const int bkb = tid >> 6;
    const int bs0 = bn*64 + (((bkb*2)     ^ (bn & 7)) * 8);
    const int bs1 = bn*64 + (((bkb*2 + 1) ^ (bn & 7)) * 8);
    f32x4 acc[4][4] = {};
    for (int k0 = 0; k0 < H_DIM; k0 += 64) {
      #pragma unroll
      for (int g = 0; g < 8; g++)
        gload_lds16(arp[g] + k0, &As[(wm + g*8)*64]);
      {
        const float* gb = B + (size_t)(k0 + bkb*16) * FF2 + (n0 + bn);
        float f[16];
        #pragma unroll
        for (int j = 0; j < 16; j++) f[j] = gb[(size_t)j * FF2];
        u32 pk[8];
        #pragma unroll
        for (int j = 0; j < 8; j++)
          pk[j] = __builtin_bit_cast(u32, __builtin_amdgcn_cvt_pkrtz(f[2*j], f[2*j+1]));
        *(uint4*)&Bs[bs0] = make_uint4(pk[0], pk[1], pk[2], pk[3]);
        *(uint4*)&Bs[bs1] = make_uint4(pk[4], pk[5], pk[6], pk[7]);
      }
      asm volatile("s_waitcnt vmcnt(0) lgkmcnt(0)" ::: "memory");
      __syncthreads();
      #pragma unroll
      for (int kk = 0; kk < 2; kk++) {
        const int cb = fg + kk*4;
        f16x8 a[4], b[4];
        #pragma unroll
        for (int m = 0; m < 4; m++) {
          const int r = wm + m*16 + fr;
          a[m] = *(const f16x8*)&As[r*64 + ((cb ^ (r & 7)) * 8)];
        }
        #pragma unroll
        for (int n = 0; n < 4; n++) {
          const int r = n*16 + fr;
          b[n] = *(const f16x8*)&Bs[r*64 + ((cb ^ (r & 7)) * 8)];
        }
        #pragma unroll
        for (int n = 0; n < 4; n++)
          #pragma unroll
          for (int m = 0; m < 4; m++)
            acc[m][n] = __builtin_amdgcn_mfma_f32_16x16x32_f16(a[m], b[n], acc[m][n], 0,0,0);
      }
      __syncthreads();
    }
    #pragma unroll
    for (int m = 0; m < 4; m++)
      #pragma unroll
      for (int n = 0; n < 4; n++)
        #pragma unroll
        for (int j = 0; j < 4; j++) {
          int r = m0 + wm + m*16 + cr + j;
          if (r < cnt) C[(size_t)r * FF2 + (n0 + n*16 + cc)] = acc[m][n][j];
        }
  } else {
    const int m0 = (z - 32) * 256;
    f32x4 acc[4][4] = {};
    for (int k0 = 0; k0 < H_DIM; k0 += 64) {
      #pragma unroll
      for (int g = 0; g < 8; g++)
        gload_lds16(tok + (size_t)(m0 + wm + g*8 + arow)*H_DIM + k0 + acol,
                    &As[(wm + g*8)*64]);
      #pragma unroll
      for (int g = 0; g < 2; g++)
        gload_lds16(sgut + (size_t)(n0 + wave*16 + g*8 + arow)*H_DIM + k0 + acol,
                    &Bs[(wave*16 + g*8)*64]);
      asm volatile("s_waitcnt vmcnt(0) lgkmcnt(0)" ::: "memory");
      __syncthreads();
      #pragma unroll
      for (int kk = 0; kk < 2; kk++) {
        const int cb = fg + kk*4;
        f16x8 a[4], b[4];
        #pragma unroll
        for (int m = 0; m < 4; m++) {
          const int r = wm + m*16 + fr;
          a[m] = *(const f16x8*)&As[r*64 + ((cb ^ (r & 7)) * 8)];
        }
        #pragma unroll
        for (int n = 0; n < 4; n++) {
          const int r = n*16 + fr;
          b[n] = *(const f16x8*)&Bs[r*64 + ((cb ^ (r & 7)) * 8)];
        }
        #pragma unroll
        for (int n = 0; n < 4; n++)
          #pragma unroll
          for (int m = 0; m < 4; m++)
            acc[m][n] = __builtin_amdgcn_mfma_f32_16x16x32_f16(a[m], b[n], acc[m][n], 0,0,0);
      }
      __syncthreads();
    }
    #pragma unroll
    for (int m = 0; m < 4; m++)
      #pragma unroll
      for (int n = 0; n < 4; n++)
        #pragma unroll
        for (int j = 0; j < 4; j++)
          gu_sh[(size_t)(m0 + wm + m*16 + cr + j) * FF2 + (n0 + n*16 + cc)] = acc[m][n][j];
  }
}

// ---------------- gemm_dn_all: expert down (tile queue, f32 B -> y_exp) + shared down (u16 B -> out) ----------------
__global__ __launch_bounds__(256) void gemm_dn_all_kernel(
    const u16* __restrict__ Aexp, const float* __restrict__ edn, float* __restrict__ y_exp,
    const int* __restrict__ counts, const int* __restrict__ offs,
    const int* __restrict__ tile_e, const int* __restrict__ tile_m0,
    const u16* __restrict__ act_sh, const u16* __restrict__ sdnt, float* __restrict__ out_sh)
{
  __shared__ u16 As[256*64];
  __shared__ u16 Bs[64*64];
  const int z = blockIdx.z;
  const int tid = threadIdx.x, lane = tid & 63, wave = tid >> 6;
  const int n0 = blockIdx.x * 64;
  const int wm = wave * 64;
  const int arow = lane >> 3;
  const int acol = ((lane & 7) ^ arow) * 8;
  const int fr = lane & 15, fg = lane >> 4;
  const int cr = (lane >> 4) * 4, cc = lane & 15;

  if (z < 32) {
    const int e = tile_e[z];
    if (e < 0) return;
    const int m0 = tile_m0[z];
    const int cnt = counts[e];
    const int off = offs[e];
    const u16* A = Aexp + (size_t)off * FFE;
    const float* B = edn + (size_t)e * FFE * H_DIM;
    float* C = y_exp + (size_t)off * H_DIM;
    const int bn  = tid & 63;
    const int bkb = tid >> 6;
    const int bs0 = bn*64 + (((bkb*2)     ^ (bn & 7)) * 8);
    const int bs1 = bn*64 + (((bkb*2 + 1) ^ (bn & 7)) * 8);
    f32x4 acc[4][4] = {};
    for (int k0 = 0; k0 < FFE; k0 += 64) {
      #pragma unroll
      for (int g = 0; g < 8; g++)
        gload_lds16(A + (size_t)(m0 + wm + g*8 + arow)*FFE + k0 + acol,
                    &As[(wm + g*8)*64]);
      {
        const float* gb = B + (size_t)(k0 + bkb*16) * H_DIM + (n0 + bn);
        float f[16];
        #pragma unroll
        for (int j = 0; j < 16; j++) f[j] = gb[(size_t)j * H_DIM];
        u32 pk[8];
        #pragma unroll
        for (int j = 0; j < 8; j++)
          pk[j] = __builtin_bit_cast(u32, __builtin_amdgcn_cvt_pkrtz(f[2*j], f[2*j+1]));
        *(uint4*)&Bs[bs0] = make_uint4(pk[0], pk[1], pk[2], pk[3]);
        *(uint4*)&Bs[bs1] = make_uint4(pk[4], pk[5], pk[6], pk[7]);
      }
      asm volatile("s_waitcnt vmcnt(0) lgkmcnt(0)" ::: "memory");
      __syncthreads();
      #pragma unroll
      for (int kk = 0; kk < 2; kk++) {
        const int cb = fg + kk*4;
        f16x8 a[4], b[4];
        #pragma unroll
        for (int m = 0; m < 4; m++) {
          const int r = wm + m*16 + fr;
          a[m] = *(const f16x8*)&As[r*64 + ((cb ^ (r & 7)) * 8)];
        }
        #pragma unroll
        for (int n = 0; n < 4; n++) {
          const int r = n*16 + fr;
          b[n] = *(const f16x8*)&Bs[r*64 + ((cb ^ (r & 7)) * 8)];
        }
        #pragma unroll
        for (int n = 0; n < 4; n++)
          #pragma unroll
          for (int m = 0; m < 4; m++)
            acc[m][n] = __builtin_amdgcn_mfma_f32_16x16x32_f16(a[m], b[n], acc[m][n], 0,0,0);
      }
      __syncthreads();
    }
    #pragma unroll
    for (int m = 0; m < 4; m++)
      #pragma unroll
      for (int n = 0; n < 4; n++)
        #pragma unroll
        for (int j = 0; j < 4; j++) {
          int r = m0 + wm + m*16 + cr + j;
          if (r < cnt) C[(size_t)r * H_DIM + (n0 + n*16 + cc)] = acc[m][n][j];
        }
  } else {
    const int m0 = (z - 32) * 256;
    f32x4 acc[4][4] = {};
    for (int k0 = 0; k0 < FFE; k0 += 64) {
      #pragma unroll
      for (int g = 0; g < 8; g++)
        gload_lds16(act_sh + (size_t)(m0 + wm + g*8 + arow)*FFE + k0 + acol,
                    &As[(wm + g*8)*64]);
      #pragma unroll
      for (int g = 0; g < 2; g++)
        gload_lds16(sdnt + (size_t)(n0 + wave*16 + g*8 + arow)*FFE + k0 + acol,
                    &Bs[(wave*16 + g*8)*64]);
      asm volatile("s_waitcnt vmcnt(0) lgkmcnt(0)" ::: "memory");
      __syncthreads();
      #pragma unroll
      for (int kk = 0; kk < 2; kk++) {
        const int cb = fg + kk*4;
        f16x8 a[4], b[4];
        #pragma unroll
        for (int m = 0; m < 4; m++) {
          const int r = wm + m*16 + fr;
          a[m] = *(const f16x8*)&As[r*64 + ((cb ^ (r & 7)) * 8)];
        }
        #pragma unroll
        for (int n = 0; n < 4; n++) {
          const int r = n*16 + fr;
          b[n] = *(const f16x8*)&Bs[r*64 + ((cb ^ (r & 7)) * 8)];
        }
        #pragma unroll
        for (int n = 0; n < 4; n++)
          #pragma unroll
          for (int m = 0; m < 4; m++)
            acc[m][n] = __builtin_amdgcn_mfma_f32_16x16x32_f16(a[m], b[n], acc[m][n], 0,0,0);
      }
      __syncthreads();
    }
    #pragma unroll
    for (int m = 0; m < 4; m++)
      #pragma unroll
      for (int n = 0; n < 4; n++)
        #pragma unroll
        for (int j = 0; j < 4; j++)
          out_sh[(size_t)(m0 + wm + m*16 + cr + j) * H_DIM + (n0 + n*16 + cc)] = acc[m][n][j];
  }
}

// ---------------- per-head q/k rmsnorm + rope + v relayout, from fused qkv f32 ----------------
__global__ __launch_bounds__(256) void rope_kernel(
    const float* __restrict__ qkv,
    const float* __restrict__ cosb, const float* __restrict__ sinb,
    const float* __restrict__ qnw, const float* __restrict__ knw,
    u16* __restrict__ qrh, u16* __restrict__ qrl,
    u16* __restrict__ krh, u16* __restrict__ krl,
    u16* __restrict__ vth, u16* __restrict__ vtl)
{
  const int jid = blockIdx.x * 4 + (threadIdx.x >> 6);
  const int lane = threadIdx.x & 63;
  const int t = jid / 24, r = jid - t*24;
  const int b = t >> 10, s = t & (S_LEN - 1);
  const float* row = qkv + (size_t)t * 3072;
  if (r < NHEAD + NKVH) {
    const bool isq = (r < NHEAD);
    const int h = isq ? r : (r - NHEAD);
    const float* x = row + (isq ? h*DHEAD : (2048 + h*DHEAD));
    const float* nw = isq ? qnw : knw;
    float x0 = x[lane], x1 = x[lane + 64];
    float ss = x0*x0 + x1*x1;
    #pragma unroll
    for (int d = 1; d < 64; d <<= 1) ss += __shfl_xor(ss, d, 64);
    float rinv = rsqrtf(ss * (1.0f/DHEAD) + EPSF);
    float n0 = x0*rinv*nw[lane], n1 = x1*rinv*nw[lane + 64];
    float o0 = n0*cosb[s*DHEAD + lane]      - n1*sinb[s*DHEAD + lane];
    float o1 = n1*cosb[s*DHEAD + lane + 64] + n0*sinb[s*DHEAD + lane + 64];
    size_t base = isq ? ((size_t)(b*NHEAD + h)*S_LEN + s)*DHEAD
                      : ((size_t)(b*NKVH + h)*S_LEN + s)*DHEAD;
    u16* dh = isq ? qrh : krh;
    u16* dl = isq ? qrl : krl;
    u16 hh, ll;
    split2(o0, hh, ll); dh[base + lane]      = hh; dl[base + lane]      = ll;
    split2(o1, hh, ll); dh[base + lane + 64] = hh; dl[base + lane + 64] = ll;
  } else {
    const int h = r - NHEAD - NKVH;
    const float* x = row + 2560 + h*DHEAD;
    size_t base = (size_t)(b*NKVH + h)*DHEAD*S_LEN + s;
    u16 hh, ll;
    split2(x[lane], hh, ll);
    vth[base + (size_t)lane*S_LEN] = hh; vtl[base + (size_t)lane*S_LEN] = ll;
    split2(x[lane + 64], hh, ll);
    vth[base + (size_t)(lane + 64)*S_LEN] = hh; vtl[base + (size_t)(lane + 64)*S_LEN] = ll;
  }
}

// ---------------- flash attention, causal, GQA; f16 hi/lo 3-term; PAIRED q-tiles for balance ----------------
__global__ __launch_bounds__(256) void attn_kernel(
    const u16* __restrict__ qrh, const u16* __restrict__ qrl,
    const u16* __restrict__ krh, const u16* __restrict__ krl,
    const u16* __restrict__ vth, const u16* __restrict__ vtl,
    u16* __restrict__ oh, u16* __restrict__ ol)
{
  __shared__ u16 Kh[64*128], Kl[64*128];
  __shared__ u16 Vh[128*64], Vl[128*64];
  __shared__ u16 Ph[4*16*64], Pl[4*16*64];
  const int bx = blockIdx.x, h = blockIdx.y, b = blockIdx.z;
  const int hkv = h >> 2;
  const int lane = threadIdx.x & 63, wave = threadIdx.x >> 6;
  const int fr = lane & 15, fg = lane >> 4;
  const u16* qbh = qrh + ((size_t)(b*NHEAD + h)*S_LEN)*DHEAD;
  const u16* qbl = qrl + ((size_t)(b*NHEAD + h)*S_LEN)*DHEAD;
  const u16* kbh = krh + ((size_t)(b*NKVH + hkv)*S_LEN)*DHEAD;
  const u16* kbl = krl + ((size_t)(b*NKVH + hkv)*S_LEN)*DHEAD;
  const u16* vbh = vth + ((size_t)(b*NKVH + hkv)*DHEAD)*S_LEN;
  const u16* vbl = vtl + ((size_t)(b*NKVH + hkv)*DHEAD)*S_LEN;
  const float scl = 0.08838834764831845f;

  for (int it = 0; it < 2; it++) {
    const int qt = it ? (15 - bx) : bx;
    const int q0 = qt * 64;
    f16x8 aqh[4], aql[4];
    {
      const size_t qrow = (size_t)(q0 + wave*16 + fr)*DHEAD;
      #pragma unroll
      for (int kk = 0; kk < 4; kk++) {
        aqh[kk] = *(const f16x8*)&qbh[qrow + kk*32 + fg*8];
        aql[kk] = *(const f16x8*)&qbl[qrow + kk*32 + fg*8];
      }
    }
    f32x4 o0[8] = {}, o1[8] = {};
    float mrow[4] = {-1e30f,-1e30f,-1e30f,-1e30f};
    float lrow[4] = {0.f,0.f,0.f,0.f};
    for (int jt = 0; jt <= qt; jt++) {
      const int j0 = jt * 64;
      #pragma unroll
      for (int p = 0; p < 4; p++) {
        const int ck = p*4 + wave;
        gload_lds16(kbh + (size_t)(j0 + ck*4 + (lane>>4))*DHEAD + (lane&15)*8, &Kh[ck*512]);
        gload_lds16(kbl + (size_t)(j0 + ck*4 + (lane>>4))*DHEAD + (lane&15)*8, &Kl[ck*512]);
        gload_lds16(vbh + (size_t)(ck*8 + (lane>>3))*S_LEN + j0 + (lane&7)*8, &Vh[ck*512]);
        gload_lds16(vbl + (size_t)(ck*8 + (lane>>3))*S_LEN + j0 + (lane&7)*8, &Vl[ck*512]);
      }
      __syncthreads();
      f32x4 s0[4] = {}, s1[4] = {};
      #pragma unroll
      for (int kk = 0; kk < 4; kk++) {
        const int ko = kk*32 + fg*8;
        #pragma unroll
        for (int n = 0; n < 4; n++) {
          f16x8 bh_ = *(const f16x8*)&Kh[(n*16 + fr)*128 + ko];
          f16x8 bl_ = *(const f16x8*)&Kl[(n*16 + fr)*128 + ko];
          s0[n] = __builtin_amdgcn_mfma_f32_16x16x32_f16(aqh[kk], bh_, s0[n], 0,0,0);
          s1[n] = __builtin_amdgcn_mfma_f32_16x16x32_f16(aqh[kk], bl_, s1[n], 0,0,0);
          s1[n] = __builtin_amdgcn_mfma_f32_16x16x32_f16(aql[kk], bh_, s1[n], 0,0,0);
        }
      }
      const int rb = q0 + wave*16 + fg*4;
      float pv[4][4];
      #pragma unroll
      for (int n = 0; n < 4; n++)
        #pragma unroll
        for (int j = 0; j < 4; j++) {
          float v = (s0[n][j] + s1[n][j]*(1.0f/2048.0f)) * scl;
          if (j0 + n*16 + fr > rb + j) v = -1e30f;
          pv[n][j] = v;
        }
      float alpha[4];
      #pragma unroll
      for (int j = 0; j < 4; j++) {
        float mx = fmaxf(fmaxf(pv[0][j], pv[1][j]), fmaxf(pv[2][j], pv[3][j]));
        #pragma unroll
        for (int d = 1; d < 16; d <<= 1) mx = fmaxf(mx, __shfl_xor(mx, d, 64));
        float mnew = fmaxf(mrow[j], mx);
        alpha[j] = __expf(mrow[j] - mnew);
        mrow[j] = mnew;
      }
      float rsum[4] = {0.f,0.f,0.f,0.f};
      #pragma unroll
      for (int n = 0; n < 4; n++)
        #pragma unroll
        for (int j = 0; j < 4; j++) {
          float p = __expf(pv[n][j] - mrow[j]);
          pv[n][j] = p;
          rsum[j] += p;
        }
      #pragma unroll
      for (int j = 0; j < 4; j++) {
        #pragma unroll
        for (int d = 1; d < 16; d <<= 1) rsum[j] += __shfl_xor(rsum[j], d, 64);
        lrow[j] = lrow[j]*alpha[j] + rsum[j];
      }
      #pragma unroll
      for (int n2 = 0; n2 < 8; n2++)
        #pragma unroll
        for (int j = 0; j < 4; j++) { o0[n2][j] *= alpha[j]; o1[n2][j] *= alpha[j]; }
      #pragma unroll
      for (int n = 0; n < 4; n++)
        #pragma unroll
        for (int j = 0; j < 4; j++) {
          u16 hh, ll; split2(pv[n][j], hh, ll);
          Ph[wave*1024 + (fg*4 + j)*64 + n*16 + fr] = hh;
          Pl[wave*1024 + (fg*4 + j)*64 + n*16 + fr] = ll;
        }
      __syncthreads();
      #pragma unroll
      for (int kk = 0; kk < 2; kk++) {
        const int ko = kk*32 + fg*8;
        f16x8 ah_ = *(const f16x8*)&Ph[wave*1024 + fr*64 + ko];
        f16x8 al_ = *(const f16x8*)&Pl[wave*1024 + fr*64 + ko];
        #pragma unroll
        for (int n2 = 0; n2 < 8; n2++) {
          f16x8 vh_ = *(const f16x8*)&Vh[(n2*16 + fr)*64 + ko];
          f16x8 vl_ = *(const f16x8*)&Vl[(n2*16 + fr)*64 + ko];
          o0[n2] = __builtin_amdgcn_mfma_f32_16x16x32_f16(ah_, vh_, o0[n2], 0,0,0);
          o1[n2] = __builtin_amdgcn_mfma_f32_16x16x32_f16(ah_, vl_, o1[n2], 0,0,0);
          o1[n2] = __builtin_amdgcn_mfma_f32_16x16x32_f16(al_, vh_, o1[n2], 0,0,0);
        }
      }
      __syncthreads();
    }
    float inv[4];
    #pragma unroll
    for (int j = 0; j < 4; j++) inv[j] = 1.0f / lrow[j];
    #pragma unroll
    for (int n2 = 0; n2 < 8; n2++)
      #pragma unroll
      for (int j = 0; j < 4; j++) {
        int s = q0 + wave*16 + fg*4 + j;
        size_t idx = ((size_t)(b*S_LEN + s))*H_DIM + h*DHEAD + n2*16 + fr;
        float val = (o0[n2][j] + o1[n2][j]*(1.0f/2048.0f)) * inv[j];
        u16 hh, ll; split2(val, hh, ll);
        oh[idx] = hh; ol[idx] = ll;
      }
  }
}

// ---------------- router: 256 thr / 4 waves; each wave computes 4 expert logits ----------------
__global__ __launch_bounds__(256) void router_kernel(
    const float* __restrict__ resid, const float* __restrict__ ln2w,
    const float* __restrict__ gw, int* __restrict__ ids, float* __restrict__ wts,
    int* __restrict__ counts)
{
  __shared__ float lgs[NEXP];
  const int t = blockIdx.x, tid = threadIdx.x;
  const int lane = tid & 63, wave = tid >> 6;
  const float* x = resid + (size_t)t * H_DIM;
  float xv[32];
  float ss = 0.f;
  #pragma unroll
  for (int p = 0; p < 8; p++) {
    float4 v  = *(const float4*)&x[p*256 + lane*4];
    float4 lw = *(const float4*)&ln2w[p*256 + lane*4];
    ss += v.x*v.x + v.y*v.y + v.z*v.z + v.w*v.w;
    xv[p*4+0] = v.x*lw.x; xv[p*4+1] = v.y*lw.y; xv[p*4+2] = v.z*lw.z; xv[p*4+3] = v.w*lw.w;
  }
  #pragma unroll
  for (int d = 1; d < 64; d <<= 1) ss += __shfl_xor(ss, d, 64);
  const float rinv = rsqrtf(ss * (1.0f/H_DIM) + EPSF);
  #pragma unroll
  for (int i = 0; i < 4; i++) {
    const int e = wave*4 + i;
    const float* g = gw + (size_t)e * H_DIM;
    float dacc = 0.f;
    #pragma unroll
    for (int p = 0; p < 8; p++) {
      float4 gv = *(const float4*)&g[p*256 + lane*4];
      dacc += xv[p*4+0]*gv.x + xv[p*4+1]*gv.y + xv[p*4+2]*gv.z + xv[p*4+3]*gv.w;
    }
    #pragma unroll
    for (int d = 1; d < 64; d <<= 1) dacc += __shfl_xor(dacc, d, 64);
    if (lane == 0) lgs[e] = dacc * rinv;
  }
  __syncthreads();
  if (tid == 0) {
    float lg[NEXP];
    #pragma unroll
    for (int e = 0; e < NEXP; e++) lg[e] = lgs[e];
    int i0 = 0; float b0 = lg[0];
    #pragma unroll
    for (int e = 1; e < NEXP; e++) if (lg[e] > b0) { b0 = lg[e]; i0 = e; }
    int i1 = -1; float b1 = -3e38f;
    #pragma unroll
    for (int e = 0; e < NEXP; e++) if (e != i0 && lg[e] > b1) { b1 = lg[e]; i1 = e; }
    float rr = __expf(b1 - b0);
    float w0 = 1.0f / (1.0f + rr);
    ids[t*2] = i0; ids[t*2+1] = i1;
    wts[t*2] = w0; wts[t*2+1] = rr * w0;
    atomicAdd(&counts[i0], 1);
    atomicAdd(&counts[i1], 1);
  }
}

__global__ void scan_kernel(const int* __restrict__ counts, int* __restrict__ offs,
                            int* __restrict__ cursor,
                            int* __restrict__ tile_e, int* __restrict__ tile_m0)
{
  if (threadIdx.x == 0) {
    int s = 0, nt = 0;
    for (int e = 0; e < NEXP; e++) {
      offs[e] = s; cursor[e] = 0;
      int c = counts[e];
      for (int m0 = 0; m0 < c; m0 += 256) { tile_e[nt] = e; tile_m0[nt] = m0; nt++; }
      s += c;
    }
    for (; nt < 32; nt++) { tile_e[nt] = -1; tile_m0[nt] = 0; }
  }
}

__global__ __launch_bounds__(256) void scatter_kernel(
    const int* __restrict__ ids, const int* __restrict__ offs,
    int* __restrict__ cursor, int* __restrict__ list, int* __restrict__ pos)
{
  int t = blockIdx.x * 256 + threadIdx.x;
  if (t < T_TOK) {
    for (int kk = 0; kk < 2; kk++) {
      int e = ids[t*2 + kk];
      int p = atomicAdd(&cursor[e], 1);
      int i = offs[e] + p;
      list[i] = t;
      pos[t*2 + kk] = i;
    }
  }
}

// ---------------- silu_all: expert rows (0..4095) + shared rows (4096..6143) ----------------
__global__ __launch_bounds__(256) void silu_all_kernel(
    const float* __restrict__ gu_exp, u16* __restrict__ act_ex,
    const float* __restrict__ gu_sh,  u16* __restrict__ act_sh)
{
  const int rr = blockIdx.x;
  const float* g;
  u16* o;
  if (rr < 2*T_TOK) { g = gu_exp + (size_t)rr * FF2;          o = act_ex + (size_t)rr * FFE; }
  else              { g = gu_sh  + (size_t)(rr - 2*T_TOK) * FF2; o = act_sh + (size_t)(rr - 2*T_TOK) * FFE; }
  for (int c = threadIdx.x*4; c < FFE; c += 1024) {
    float4 gv = *(const float4*)&g[c];
    float4 uv = *(const float4*)&g[c + FFE];
    float s0 = gv.x / (1.0f + __expf(-gv.x)) * uv.x;
    float s1 = gv.y / (1.0f + __expf(-gv.y)) * uv.y;
    float s2 = gv.z / (1.0f + __expf(-gv.z)) * uv.z;
    float s3 = gv.w / (1.0f + __expf(-gv.w)) * uv.w;
    u32 lo = (u32)f2h(s0) | ((u32)f2h(s1) << 16);
    u32 hi = (u32)f2h(s2) | ((u32)f2h(s3) << 16);
    *(uint2*)&o[c] = make_uint2(lo, hi);
  }
}

// out = out(shared) + w0*y[p0] + w1*y[p1]   (in-place RMW on d_out)
__global__ __launch_bounds__(256) void combine_kernel(
    const float* __restrict__ y,
    const int* __restrict__ pos, const float* __restrict__ wts,
    float* __restrict__ out)
{
  const int t = blockIdx.x;
  const int p0 = pos[t*2], p1 = pos[t*2+1];
  const float w0 = wts[t*2] * RSF_C, w1 = wts[t*2+1] * RSF_C;
  const int c = threadIdx.x * 8;
  #pragma unroll
  for (int q = 0; q < 2; q++) {
    const int cc = c + q*4;
    float4 s  = *(const float4*)&out[(size_t)t*H_DIM + cc];
    float4 a  = *(const float4*)&y[(size_t)p0*H_DIM + cc];
    float4 bb = *(const float4*)&y[(size_t)p1*H_DIM + cc];
    float4 r;
    r.x = s.x + w0*a.x + w1*bb.x;
    r.y = s.y + w0*a.y + w1*bb.y;
    r.z = s.z + w0*a.z + w1*bb.z;
    r.w = s.w + w0*a.w + w1*bb.w;
    *(float4*)&out[(size_t)t*H_DIM + cc] = r;
  }
}

extern "C" void kernel_launch(void* const* d_in, const int* in_sizes, int n_in,
                              void* d_out, int out_size, void* d_ws, size_t ws_size,
                              hipStream_t stream)
{
  (void)in_sizes; (void)n_in; (void)out_size;
  const float* hidden = (const float*)d_in[0];
  const float* cosb   = (const float*)d_in[1];
  const float* sinb   = (const float*)d_in[2];
  const float* ln1w   = (const float*)d_in[3];
  const float* ln2w   = (const float*)d_in[4];
  const float* qnw    = (const float*)d_in[5];
  const float* knw    = (const float*)d_in[6];
  const float* wq     = (const float*)d_in[7];
  const float* wk     = (const float*)d_in[8];
  const float* wv     = (const float*)d_in[9];
  const float* wo     = (const float*)d_in[10];
  const float* gw     = (const float*)d_in[11];
  const float* egu    = (const float*)d_in[12];
  const float* edn    = (const float*)d_in[13];
  const float* sgu    = (const float*)d_in[14];
  const float* sdn    = (const float*)d_in[15];
  float* out_hidden = (float*)d_out;
  float* resid = (float*)d_out + (size_t)T_TOK * H_DIM;

  char* ws = (char*)d_ws;
  // ---- phase A (pre-router) ----
  constexpr size_t OFF_XH    = 0;
  constexpr size_t OFF_XL    = 8388608;
  constexpr size_t OFF_WQKVH = 16777216;
  constexpr size_t OFF_WQKVL = 29360128;
  constexpr size_t OFF_WOH   = 41943040;
  constexpr size_t OFF_WOL   = 50331648;
  constexpr size_t OFF_QKV   = 58720256;   // 25,165,824 f32 [2048][3072]
  constexpr size_t OFF_QRH = 16777216, OFF_QRL = 25165824;
  constexpr size_t OFF_KRH = 33554432, OFF_KRL = 35651584;
  constexpr size_t OFF_VTH = 37748736, OFF_VTL = 39845888;
  constexpr size_t OFF_OH = 58720256, OFF_OL = 67108864;
  // ---- phase B (post-router) ----
  constexpr size_t OFF_GUE = 0;            // gu_exp 46,137,344 ; later y_exp 33,554,432
  constexpr size_t OFF_TOK = 63963136;     // 8,388,608
  constexpr size_t OFF_ACE = 72351744;     // act_ex (4096+256)x1408x2 = 12,255,232
  constexpr size_t OFF_GUS = 84606976;     // 23,068,672
  constexpr size_t OFF_ACS = 107675648;    // 5,767,168
  constexpr size_t OFF_SGUT= 113442816;    // 11,534,336
  constexpr size_t OFF_SDNT= 124977152;    // 5,767,168
  constexpr size_t OFF_IDS = 130744320;
  constexpr size_t OFF_WTS = OFF_IDS + 16384;
  constexpr size_t OFF_POS = OFF_WTS + 16384;
  constexpr size_t OFF_LST = OFF_POS + 16384;
  constexpr size_t OFF_CNT = OFF_LST + 16384;
  constexpr size_t OFF_OFS = OFF_CNT + 64;
  constexpr size_t OFF_CUR = OFF_OFS + 64;
  constexpr size_t OFF_TE  = OFF_CUR + 64;
  constexpr size_t OFF_TM  = OFF_TE + 128;
  constexpr size_t WS_NEED = OFF_TM + 128;
  if (ws_size < WS_NEED) return;

  u16* xh     = (u16*)(ws + OFF_XH);
  u16* xl     = (u16*)(ws + OFF_XL);
  u16* wqkvh  = (u16*)(ws + OFF_WQKVH);
  u16* wqkvl  = (u16*)(ws + OFF_WQKVL);
  u16* woh    = (u16*)(ws + OFF_WOH);
  u16* wol    = (u16*)(ws + OFF_WOL);
  float* qkv  = (float*)(ws + OFF_QKV);
  u16* q_rh = (u16*)(ws + OFF_QRH);
  u16* q_rl = (u16*)(ws + OFF_QRL);
  u16* k_rh = (u16*)(ws + OFF_KRH);
  u16* k_rl = (u16*)(ws + OFF_KRL);
  u16* v_th = (u16*)(ws + OFF_VTH);
  u16* v_tl = (u16*)(ws + OFF_VTL);
  u16* o_h  = (u16*)(ws + OFF_OH);
  u16* o_l  = (u16*)(ws + OFF_OL);
  float* gu_exp = (float*)(ws + OFF_GUE);
  float* y_exp  = (float*)(ws + OFF_GUE);
  u16* tok      = (u16*)(ws + OFF_TOK);
  u16* act_ex   = (u16*)(ws + OFF_ACE);
  float* gu_sh  = (float*)(ws + OFF_GUS);
  u16* act_sh   = (u16*)(ws + OFF_ACS);
  u16* sgut     = (u16*)(ws + OFF_SGUT);
  u16* sdnt     = (u16*)(ws + OFF_SDNT);
  int* ids    = (int*)(ws + OFF_IDS);
  float* wts  = (float*)(ws + OFF_WTS);
  int* pos    = (int*)(ws + OFF_POS);
  int* list   = (int*)(ws + OFF_LST);
  int* counts = (int*)(ws + OFF_CNT);
  int* offs   = (int*)(ws + OFF_OFS);
  int* cursor = (int*)(ws + OFF_CUR);
  int* tile_e = (int*)(ws + OFF_TE);
  int* tile_m0= (int*)(ws + OFF_TM);

  hipMemsetAsync(counts, 0, 64, stream);

  // ---- prep: all weight transpose/split jobs in ONE launch ----
  tsplit_all_kernel<<<dim3(44,32,6), 256, 0, stream>>>(wq, wk, wv, wo, sgu, sdn,
                                                       wqkvh, wqkvl, woh, wol, sgut, sdnt);

  // ---- pre-router chain (f16 hi/lo precision) ----
  rmsnorm_kernel<<<T_TOK, 256, 0, stream>>>(hidden, ln1w, xh, xl);
  gemm3b_kernel<<<dim3(24,16), 256, 0, stream>>>(xh, xl, H_DIM, wqkvh, wqkvl, 2048, qkv, 3072, nullptr, H_DIM);
  rope_kernel<<<(T_TOK*24)/4, 256, 0, stream>>>(qkv, cosb, sinb, qnw, knw,
                                                q_rh, q_rl, k_rh, k_rl, v_th, v_tl);
  attn_kernel<<<dim3(8, NHEAD, NB), 256, 0, stream>>>(q_rh, q_rl, k_rh, k_rl, v_th, v_tl, o_h, o_l);
  gemm3b_kernel<<<dim3(16,16), 256, 0, stream>>>(o_h, o_l, H_DIM, woh, wol, 2048, resid, H_DIM, hidden, H_DIM);

  // ---- router ----
  rmsnorm_kernel<<<T_TOK, 256, 0, stream>>>(resid, ln2w, tok, nullptr);
  router_kernel<<<T_TOK, 256, 0, stream>>>(resid, ln2w, gw, ids, wts, counts);
  scan_kernel<<<1, 64, 0, stream>>>(counts, offs, cursor, tile_e, tile_m0);
  scatter_kernel<<<8, 256, 0, stream>>>(ids, offs, cursor, list, pos);

  // ---- MoE: merged up (indirect A from tok via list -- no gather), merged silu, merged down, combine ----
  gemm_up_all_kernel<<<dim3(44,1,40), 256, 0, stream>>>(list, egu, gu_exp,
                                                        counts, offs, tile_e, tile_m0,
                                                        tok, sgut, gu_sh);
  silu_all_kernel<<<3*T_TOK, 256, 0, stream>>>(gu_exp, act_ex, gu_sh, act_sh);
  gemm_dn_all_kernel<<<dim3(32,1,40), 256, 0, stream>>>(act_ex, edn, y_exp,
                                                        counts, offs, tile_e, tile_m0,
                                                        act_sh, sdnt, out_hidden);
  combine_kernel<<<T_TOK, 256, 0, stream>>>(y_exp, pos, wts, out_hidden);
}

// Round 24
// 727.898 us; speedup vs baseline: 1.1163x; 1.0115x over previous
//
#include <hip/hip_runtime.h>
#include <stdint.h>

typedef unsigned short u16;
typedef unsigned int   u32;
typedef __attribute__((ext_vector_type(4))) float     f32x4;
typedef __attribute__((ext_vector_type(8))) _Float16  f16x8;

#define S_LEN 1024
#define NB    2
#define H_DIM 2048
#define T_TOK 2048
#define NHEAD 16
#define NKVH  4
#define DHEAD 128
#define NEXP  16
#define FFE   1408
#define FF2   2816
#define EPSF  1e-5f
#define RSF_C 1.0f

// ---- f32 <-> f16 helpers (scaled hi/lo split: x ~= hi + lo/2048) ----
__device__ __forceinline__ u16 f2h(float f){
  _Float16 h = (_Float16)f;
  return __builtin_bit_cast(unsigned short, h);
}
__device__ __forceinline__ void split2(float f, u16& hi, u16& lo){
  _Float16 h = (_Float16)f;
  hi = __builtin_bit_cast(unsigned short, h);
  _Float16 l = (_Float16)((f - (float)h) * 2048.0f);
  lo = __builtin_bit_cast(unsigned short, l);
}
__device__ __forceinline__ void gload_lds16(const void* g, void* l){
  __builtin_amdgcn_global_load_lds((const __attribute__((address_space(1))) void*)g,
                                   (__attribute__((address_space(3))) void*)l, 16, 0, 0);
}
__device__ __forceinline__ uint4 pack8(const u16* p){
  return make_uint4((u32)p[0] | ((u32)p[1]<<16), (u32)p[2] | ((u32)p[3]<<16),
                    (u32)p[4] | ((u32)p[5]<<16), (u32)p[6] | ((u32)p[7]<<16));
}

// ---------------- tsplit_all: all six weight transpose/split jobs in one launch ----------------
// z: 0=wq 1=wk 2=wv 3=wo (dual) 4=sgu 5=sdn (single). grid (44,32,6); oversized blocks exit early.
__global__ __launch_bounds__(256) void tsplit_all_kernel(
    const float* __restrict__ wq, const float* __restrict__ wk,
    const float* __restrict__ wv, const float* __restrict__ wo,
    const float* __restrict__ sgu, const float* __restrict__ sdn,
    u16* __restrict__ wqkvh, u16* __restrict__ wqkvl,
    u16* __restrict__ woh,  u16* __restrict__ wol,
    u16* __restrict__ sgut, u16* __restrict__ sdnt)
{
  const int z = blockIdx.z;
  const float* in; int ldn; u16* outh; u16* outl; int ldk, nx, ny; bool dual;
  switch (z) {
    case 0:  in=wq;  ldn=2048; outh=wqkvh;              outl=wqkvl;              ldk=2048; nx=32; ny=32; dual=true;  break;
    case 1:  in=wk;  ldn=512;  outh=wqkvh+2048*2048;    outl=wqkvl+2048*2048;    ldk=2048; nx=8;  ny=32; dual=true;  break;
    case 2:  in=wv;  ldn=512;  outh=wqkvh+2560*2048;    outl=wqkvl+2560*2048;    ldk=2048; nx=8;  ny=32; dual=true;  break;
    case 3:  in=wo;  ldn=2048; outh=woh;                outl=wol;                ldk=2048; nx=32; ny=32; dual=true;  break;
    case 4:  in=sgu; ldn=2816; outh=sgut;               outl=nullptr;            ldk=2048; nx=44; ny=32; dual=false; break;
    default: in=sdn; ldn=2048; outh=sdnt;               outl=nullptr;            ldk=1408; nx=32; ny=22; dual=false; break;
  }
  if ((int)blockIdx.x >= nx || (int)blockIdx.y >= ny) return;
  __shared__ float tile[64][65];
  const int n0 = blockIdx.x * 64, k0 = blockIdx.y * 64;
  const int tid = threadIdx.x;
  const int tr = tid >> 4, tc = (tid & 15) * 4;
  #pragma unroll
  for (int i = 0; i < 4; i++) {
    float4 v = *(const float4*)&in[(size_t)(k0 + tr + i*16) * ldn + (n0 + tc)];
    tile[tr + i*16][tc+0] = v.x; tile[tr + i*16][tc+1] = v.y;
    tile[tr + i*16][tc+2] = v.z; tile[tr + i*16][tc+3] = v.w;
  }
  __syncthreads();
  const int n = tid >> 2, kg = (tid & 3) * 16;
  u16 hb[16], lb[16];
  #pragma unroll
  for (int j = 0; j < 16; j++) {
    float f = tile[kg + j][n];
    if (dual) split2(f, hb[j], lb[j]); else hb[j] = f2h(f);
  }
  u16* dh = &outh[(size_t)(n0 + n) * ldk + k0 + kg];
  *(uint4*)dh       = pack8(hb);
  *(uint4*)(dh + 8) = pack8(hb + 8);
  if (dual) {
    u16* dl = &outl[(size_t)(n0 + n) * ldk + k0 + kg];
    *(uint4*)dl       = pack8(lb);
    *(uint4*)(dl + 8) = pack8(lb + 8);
  }
}

// ---------------- RMSNorm: f32 in -> f16 hi (+optional scaled lo) ----------------
__global__ __launch_bounds__(256) void rmsnorm_kernel(
    const float* __restrict__ in, const float* __restrict__ w,
    u16* __restrict__ outh, u16* __restrict__ outl)
{
  __shared__ float red[4];
  const int t = blockIdx.x, tid = threadIdx.x;
  const int lane = tid & 63, wave = tid >> 6;
  const float* x = in + (size_t)t * H_DIM;
  const int c = tid * 8;
  float4 v0 = *(const float4*)&x[c];
  float4 v1 = *(const float4*)&x[c + 4];
  float ss = v0.x*v0.x + v0.y*v0.y + v0.z*v0.z + v0.w*v0.w
           + v1.x*v1.x + v1.y*v1.y + v1.z*v1.z + v1.w*v1.w;
  #pragma unroll
  for (int d = 1; d < 64; d <<= 1) ss += __shfl_xor(ss, d, 64);
  if (lane == 0) red[wave] = ss;
  __syncthreads();
  float rinv = rsqrtf((red[0]+red[1]+red[2]+red[3]) * (1.0f/H_DIM) + EPSF);
  float4 w0 = *(const float4*)&w[c];
  float4 w1 = *(const float4*)&w[c + 4];
  float vals[8] = { v0.x*rinv*w0.x, v0.y*rinv*w0.y, v0.z*rinv*w0.z, v0.w*rinv*w0.w,
                    v1.x*rinv*w1.x, v1.y*rinv*w1.y, v1.z*rinv*w1.z, v1.w*rinv*w1.w };
  u16 hb[8], lb[8];
  #pragma unroll
  for (int j = 0; j < 8; j++) split2(vals[j], hb[j], lb[j]);
  *(uint4*)&outh[(size_t)t * H_DIM + c] = pack8(hb);
  if (outl) *(uint4*)&outl[(size_t)t * H_DIM + c] = pack8(lb);
}

// ---------------- gemm3b: C(f32) = (Ah+Al/2048) @ (Bh+Bl/2048)^T; BK=64, swizzled LDS ----------------
__global__ __launch_bounds__(256) void gemm3b_kernel(
    const u16* __restrict__ Ah, const u16* __restrict__ Al, int lda,
    const u16* __restrict__ Bh, const u16* __restrict__ Bl, int ldb,
    float* __restrict__ C, int ldc,
    const float* __restrict__ addsrc, int K)
{
  __shared__ u16 Ash[128*64], Asl[128*64];
  __shared__ u16 Bsh[128*64], Bsl[128*64];
  const int tid = threadIdx.x, lane = tid & 63, wave = tid >> 6;
  const int m0 = blockIdx.y * 128, n0 = blockIdx.x * 128;
  const int wm = (wave >> 1) * 64, wn = (wave & 1) * 64;
  const int arow = lane >> 3;
  const int acol = ((lane & 7) ^ arow) * 8;
  f32x4 acc0[4][4] = {}, acc1[4][4] = {};
  for (int k0 = 0; k0 < K; k0 += 64) {
    #pragma unroll
    for (int g = 0; g < 4; g++) {
      const int rb = wave*32 + g*8;
      gload_lds16(Ah + (size_t)(m0 + rb + arow)*lda + k0 + acol, &Ash[rb*64]);
      gload_lds16(Al + (size_t)(m0 + rb + arow)*lda + k0 + acol, &Asl[rb*64]);
      gload_lds16(Bh + (size_t)(n0 + rb + arow)*ldb + k0 + acol, &Bsh[rb*64]);
      gload_lds16(Bl + (size_t)(n0 + rb + arow)*ldb + k0 + acol, &Bsl[rb*64]);
    }
    asm volatile("s_waitcnt vmcnt(0) lgkmcnt(0)" ::: "memory");
    __syncthreads();
    const int fr = lane & 15, fg = lane >> 4;
    #pragma unroll
    for (int kk = 0; kk < 2; kk++) {
      const int cb = fg + kk*4;
      f16x8 ah[4], al[4];
      #pragma unroll
      for (int m = 0; m < 4; m++) {
        const int r = wm + m*16 + fr;
        const int s = (cb ^ (r & 7)) * 8;
        ah[m] = *(const f16x8*)&Ash[r*64 + s];
        al[m] = *(const f16x8*)&Asl[r*64 + s];
      }
      #pragma unroll
      for (int n = 0; n < 4; n++) {
        const int r = wn + n*16 + fr;
        const int s = (cb ^ (r & 7)) * 8;
        f16x8 bh_ = *(const f16x8*)&Bsh[r*64 + s];
        f16x8 bl_ = *(const f16x8*)&Bsl[r*64 + s];
        #pragma unroll
        for (int m = 0; m < 4; m++) {
          acc0[m][n] = __builtin_amdgcn_mfma_f32_16x16x32_f16(ah[m], bh_, acc0[m][n], 0,0,0);
          acc1[m][n] = __builtin_amdgcn_mfma_f32_16x16x32_f16(ah[m], bl_, acc1[m][n], 0,0,0);
          acc1[m][n] = __builtin_amdgcn_mfma_f32_16x16x32_f16(al[m], bh_, acc1[m][n], 0,0,0);
        }
      }
    }
    __syncthreads();
  }
  const int cr = (lane >> 4) * 4, cc = lane & 15;
  #pragma unroll
  for (int m = 0; m < 4; m++)
    #pragma unroll
    for (int n = 0; n < 4; n++)
      #pragma unroll
      for (int j = 0; j < 4; j++) {
        int r = m0 + wm + m*16 + cr + j;
        size_t idx = (size_t)r * ldc + (n0 + wn + n*16 + cc);
        float v = acc0[m][n][j] + acc1[m][n][j] * (1.0f/2048.0f);
        if (addsrc) v += addsrc[idx];
        C[idx] = v;
      }
}

// ---------------- gemm_up_all: expert up (tile queue, indirect A via list, f32 B) + shared up (dense, u16 B) ----------------
// grid (44, 1, 40): z<32 -> expert tile z; z>=32 -> shared m-tile (z-32). M=256 x N=64, BK=64.
__global__ __launch_bounds__(256) void gemm_up_all_kernel(
    const int* __restrict__ list, const float* __restrict__ egu, float* __restrict__ gu_exp,
    const int* __restrict__ counts, const int* __restrict__ offs,
    const int* __restrict__ tile_e, const int* __restrict__ tile_m0,
    const u16* __restrict__ tok, const u16* __restrict__ sgut, float* __restrict__ gu_sh)
{
  __shared__ u16 As[256*64];
  __shared__ u16 Bs[64*64];
  const int z = blockIdx.z;
  const int tid = threadIdx.x, lane = tid & 63, wave = tid >> 6;
  const int n0 = blockIdx.x * 64;
  const int wm = wave * 64;
  const int arow = lane >> 3;
  const int acol = ((lane & 7) ^ arow) * 8;
  const int fr = lane & 15, fg = lane >> 4;
  const int cr = (lane >> 4) * 4, cc = lane & 15;

  if (z < 32) {
    const int e = tile_e[z];
    if (e < 0) return;
    const int m0 = tile_m0[z];
    const int cnt = counts[e];
    const int off = offs[e];
    const float* B = egu + (size_t)e * H_DIM * FF2;
    float* C = gu_exp + (size_t)off * FF2;
    const u16* arp[8];
    #pragma unroll
    for (int g = 0; g < 8; g++) {
      int idx = off + m0 + wm + g*8 + arow;
      if (idx > 2*T_TOK - 1) idx = 2*T_TOK - 1;
      arp[g] = tok + (size_t)list[idx] * H_DIM + acol;
    }
    const int bn  = tid & 63;
    const int bkb = tid >> 6;
    const int bs0 = bn*64 + (((bkb*2)     ^ (bn & 7)) * 8);
    const int bs1 = bn*64 + (((bkb*2 + 1) ^ (bn & 7)) * 8);
    f32x4 acc[4][4] = {};
    for (int k0 = 0; k0 < H_DIM; k0 += 64) {
      #pragma unroll
      for (int g = 0; g < 8; g++)
        gload_lds16(arp[g] + k0, &As[(wm + g*8)*64]);
      {
        const float* gb = B + (size_t)(k0 + bkb*16) * FF2 + (n0 + bn);
        float f[16];
        #pragma unroll
        for (int j = 0; j < 16; j++) f[j] = gb[(size_t)j * FF2];
        u32 pk[8];
        #pragma unroll
        for (int j = 0; j < 8; j++)
          pk[j] = __builtin_bit_cast(u32, __builtin_amdgcn_cvt_pkrtz(f[2*j], f[2*j+1]));
        *(uint4*)&Bs[bs0] = make_uint4(pk[0], pk[1], pk[2], pk[3]);
        *(uint4*)&Bs[bs1] = make_uint4(pk[4], pk[5], pk[6], pk[7]);
      }
      asm volatile("s_waitcnt vmcnt(0) lgkmcnt(0)" ::: "memory");
      __syncthreads();
      #pragma unroll
      for (int kk = 0; kk < 2; kk++) {
        const int cb = fg + kk*4;
        f16x8 a[4], b[4];
        #pragma unroll
        for (int m = 0; m < 4; m++) {
          const int r = wm + m*16 + fr;
          a[m] = *(const f16x8*)&As[r*64 + ((cb ^ (r & 7)) * 8)];
        }
        #pragma unroll
        for (int n = 0; n < 4; n++) {
          const int r = n*16 + fr;
          b[n] = *(const f16x8*)&Bs[r*64 + ((cb ^ (r & 7)) * 8)];
        }
        #pragma unroll
        for (int n = 0; n < 4; n++)
          #pragma unroll
          for (int m = 0; m < 4; m++)
            acc[m][n] = __builtin_amdgcn_mfma_f32_16x16x32_f16(a[m], b[n], acc[m][n], 0,0,0);
      }
      __syncthreads();
    }
    #pragma unroll
    for (int m = 0; m < 4; m++)
      #pragma unroll
      for (int n = 0; n < 4; n++)
        #pragma unroll
        for (int j = 0; j < 4; j++) {
          int r = m0 + wm + m*16 + cr + j;
          if (r < cnt) C[(size_t)r * FF2 + (n0 + n*16 + cc)] = acc[m][n][j];
        }
  } else {
    const int m0 = (z - 32) * 256;
    f32x4 acc[4][4] = {};
    for (int k0 = 0; k0 < H_DIM; k0 += 64) {
      #pragma unroll
      for (int g = 0; g < 8; g++)
        gload_lds16(tok + (size_t)(m0 + wm + g*8 + arow)*H_DIM + k0 + acol,
                    &As[(wm + g*8)*64]);
      #pragma unroll
      for (int g = 0; g < 2; g++)
        gload_lds16(sgut + (size_t)(n0 + wave*16 + g*8 + arow)*H_DIM + k0 + acol,
                    &Bs[(wave*16 + g*8)*64]);
      asm volatile("s_waitcnt vmcnt(0) lgkmcnt(0)" ::: "memory");
      __syncthreads();
      #pragma unroll
      for (int kk = 0; kk < 2; kk++) {
        const int cb = fg + kk*4;
        f16x8 a[4], b[4];
        #pragma unroll
        for (int m = 0; m < 4; m++) {
          const int r = wm + m*16 + fr;
          a[m] = *(const f16x8*)&As[r*64 + ((cb ^ (r & 7)) * 8)];
        }
        #pragma unroll
        for (int n = 0; n < 4; n++) {
          const int r = n*16 + fr;
          b[n] = *(const f16x8*)&Bs[r*64 + ((cb ^ (r & 7)) * 8)];
        }
        #pragma unroll
        for (int n = 0; n < 4; n++)
          #pragma unroll
          for (int m = 0; m < 4; m++)
            acc[m][n] = __builtin_amdgcn_mfma_f32_16x16x32_f16(a[m], b[n], acc[m][n], 0,0,0);
      }
      __syncthreads();
    }
    #pragma unroll
    for (int m = 0; m < 4; m++)
      #pragma unroll
      for (int n = 0; n < 4; n++)
        #pragma unroll
        for (int j = 0; j < 4; j++)
          gu_sh[(size_t)(m0 + wm + m*16 + cr + j) * FF2 + (n0 + n*16 + cc)] = acc[m][n][j];
  }
}

// ---------------- gemm_dn_all: expert down (tile queue, f32 B -> y_exp) + shared down (u16 B -> out) ----------------
__global__ __launch_bounds__(256) void gemm_dn_all_kernel(
    const u16* __restrict__ Aexp, const float* __restrict__ edn, float* __restrict__ y_exp,
    const int* __restrict__ counts, const int* __restrict__ offs,
    const int* __restrict__ tile_e, const int* __restrict__ tile_m0,
    const u16* __restrict__ act_sh, const u16* __restrict__ sdnt, float* __restrict__ out_sh)
{
  __shared__ u16 As[256*64];
  __shared__ u16 Bs[64*64];
  const int z = blockIdx.z;
  const int tid = threadIdx.x, lane = tid & 63, wave = tid >> 6;
  const int n0 = blockIdx.x * 64;
  const int wm = wave * 64;
  const int arow = lane >> 3;
  const int acol = ((lane & 7) ^ arow) * 8;
  const int fr = lane & 15, fg = lane >> 4;
  const int cr = (lane >> 4) * 4, cc = lane & 15;

  if (z < 32) {
    const int e = tile_e[z];
    if (e < 0) return;
    const int m0 = tile_m0[z];
    const int cnt = counts[e];
    const int off = offs[e];
    const u16* A = Aexp + (size_t)off * FFE;
    const float* B = edn + (size_t)e * FFE * H_DIM;
    float* C = y_exp + (size_t)off * H_DIM;
    const int bn  = tid & 63;
    const int bkb = tid >> 6;
    const int bs0 = bn*64 + (((bkb*2)     ^ (bn & 7)) * 8);
    const int bs1 = bn*64 + (((bkb*2 + 1) ^ (bn & 7)) * 8);
    f32x4 acc[4][4] = {};
    for (int k0 = 0; k0 < FFE; k0 += 64) {
      #pragma unroll
      for (int g = 0; g < 8; g++)
        gload_lds16(A + (size_t)(m0 + wm + g*8 + arow)*FFE + k0 + acol,
                    &As[(wm + g*8)*64]);
      {
        const float* gb = B + (size_t)(k0 + bkb*16) * H_DIM + (n0 + bn);
        float f[16];
        #pragma unroll
        for (int j = 0; j < 16; j++) f[j] = gb[(size_t)j * H_DIM];
        u32 pk[8];
        #pragma unroll
        for (int j = 0; j < 8; j++)
          pk[j] = __builtin_bit_cast(u32, __builtin_amdgcn_cvt_pkrtz(f[2*j], f[2*j+1]));
        *(uint4*)&Bs[bs0] = make_uint4(pk[0], pk[1], pk[2], pk[3]);
        *(uint4*)&Bs[bs1] = make_uint4(pk[4], pk[5], pk[6], pk[7]);
      }
      asm volatile("s_waitcnt vmcnt(0) lgkmcnt(0)" ::: "memory");
      __syncthreads();
      #pragma unroll
      for (int kk = 0; kk < 2; kk++) {
        const int cb = fg + kk*4;
        f16x8 a[4], b[4];
        #pragma unroll
        for (int m = 0; m < 4; m++) {
          const int r = wm + m*16 + fr;
          a[m] = *(const f16x8*)&As[r*64 + ((cb ^ (r & 7)) * 8)];
        }
        #pragma unroll
        for (int n = 0; n < 4; n++) {
          const int r = n*16 + fr;
          b[n] = *(const f16x8*)&Bs[r*64 + ((cb ^ (r & 7)) * 8)];
        }
        #pragma unroll
        for (int n = 0; n < 4; n++)
          #pragma unroll
          for (int m = 0; m < 4; m++)
            acc[m][n] = __builtin_amdgcn_mfma_f32_16x16x32_f16(a[m], b[n], acc[m][n], 0,0,0);
      }
      __syncthreads();
    }
    #pragma unroll
    for (int m = 0; m < 4; m++)
      #pragma unroll
      for (int n = 0; n < 4; n++)
        #pragma unroll
        for (int j = 0; j < 4; j++) {
          int r = m0 + wm + m*16 + cr + j;
          if (r < cnt) C[(size_t)r * H_DIM + (n0 + n*16 + cc)] = acc[m][n][j];
        }
  } else {
    const int m0 = (z - 32) * 256;
    f32x4 acc[4][4] = {};
    for (int k0 = 0; k0 < FFE; k0 += 64) {
      #pragma unroll
      for (int g = 0; g < 8; g++)
        gload_lds16(act_sh + (size_t)(m0 + wm + g*8 + arow)*FFE + k0 + acol,
                    &As[(wm + g*8)*64]);
      #pragma unroll
      for (int g = 0; g < 2; g++)
        gload_lds16(sdnt + (size_t)(n0 + wave*16 + g*8 + arow)*FFE + k0 + acol,
                    &Bs[(wave*16 + g*8)*64]);
      asm volatile("s_waitcnt vmcnt(0) lgkmcnt(0)" ::: "memory");
      __syncthreads();
      #pragma unroll
      for (int kk = 0; kk < 2; kk++) {
        const int cb = fg + kk*4;
        f16x8 a[4], b[4];
        #pragma unroll
        for (int m = 0; m < 4; m++) {
          const int r = wm + m*16 + fr;
          a[m] = *(const f16x8*)&As[r*64 + ((cb ^ (r & 7)) * 8)];
        }
        #pragma unroll
        for (int n = 0; n < 4; n++) {
          const int r = n*16 + fr;
          b[n] = *(const f16x8*)&Bs[r*64 + ((cb ^ (r & 7)) * 8)];
        }
        #pragma unroll
        for (int n = 0; n < 4; n++)
          #pragma unroll
          for (int m = 0; m < 4; m++)
            acc[m][n] = __builtin_amdgcn_mfma_f32_16x16x32_f16(a[m], b[n], acc[m][n], 0,0,0);
      }
      __syncthreads();
    }
    #pragma unroll
    for (int m = 0; m < 4; m++)
      #pragma unroll
      for (int n = 0; n < 4; n++)
        #pragma unroll
        for (int j = 0; j < 4; j++)
          out_sh[(size_t)(m0 + wm + m*16 + cr + j) * H_DIM + (n0 + n*16 + cc)] = acc[m][n][j];
  }
}

// ---------------- per-head q/k rmsnorm + rope + v relayout, from fused qkv f32 ----------------
__global__ __launch_bounds__(256) void rope_kernel(
    const float* __restrict__ qkv,
    const float* __restrict__ cosb, const float* __restrict__ sinb,
    const float* __restrict__ qnw, const float* __restrict__ knw,
    u16* __restrict__ qrh, u16* __restrict__ qrl,
    u16* __restrict__ krh, u16* __restrict__ krl,
    u16* __restrict__ vth, u16* __restrict__ vtl)
{
  const int jid = blockIdx.x * 4 + (threadIdx.x >> 6);
  const int lane = threadIdx.x & 63;
  const int t = jid / 24, r = jid - t*24;
  const int b = t >> 10, s = t & (S_LEN - 1);
  const float* row = qkv + (size_t)t * 3072;
  if (r < NHEAD + NKVH) {
    const bool isq = (r < NHEAD);
    const int h = isq ? r : (r - NHEAD);
    const float* x = row + (isq ? h*DHEAD : (2048 + h*DHEAD));
    const float* nw = isq ? qnw : knw;
    float x0 = x[lane], x1 = x[lane + 64];
    float ss = x0*x0 + x1*x1;
    #pragma unroll
    for (int d = 1; d < 64; d <<= 1) ss += __shfl_xor(ss, d, 64);
    float rinv = rsqrtf(ss * (1.0f/DHEAD) + EPSF);
    float n0 = x0*rinv*nw[lane], n1 = x1*rinv*nw[lane + 64];
    float o0 = n0*cosb[s*DHEAD + lane]      - n1*sinb[s*DHEAD + lane];
    float o1 = n1*cosb[s*DHEAD + lane + 64] + n0*sinb[s*DHEAD + lane + 64];
    size_t base = isq ? ((size_t)(b*NHEAD + h)*S_LEN + s)*DHEAD
                      : ((size_t)(b*NKVH + h)*S_LEN + s)*DHEAD;
    u16* dh = isq ? qrh : krh;
    u16* dl = isq ? qrl : krl;
    u16 hh, ll;
    split2(o0, hh, ll); dh[base + lane]      = hh; dl[base + lane]      = ll;
    split2(o1, hh, ll); dh[base + lane + 64] = hh; dl[base + lane + 64] = ll;
  } else {
    const int h = r - NHEAD - NKVH;
    const float* x = row + 2560 + h*DHEAD;
    size_t base = (size_t)(b*NKVH + h)*DHEAD*S_LEN + s;
    u16 hh, ll;
    split2(x[lane], hh, ll);
    vth[base + (size_t)lane*S_LEN] = hh; vtl[base + (size_t)lane*S_LEN] = ll;
    split2(x[lane + 64], hh, ll);
    vth[base + (size_t)(lane + 64)*S_LEN] = hh; vtl[base + (size_t)(lane + 64)*S_LEN] = ll;
  }
}

// ---------------- flash attention, causal, GQA; f16 hi/lo 3-term; PAIRED q-tiles for balance ----------------
__global__ __launch_bounds__(256) void attn_kernel(
    const u16* __restrict__ qrh, const u16* __restrict__ qrl,
    const u16* __restrict__ krh, const u16* __restrict__ krl,
    const u16* __restrict__ vth, const u16* __restrict__ vtl,
    u16* __restrict__ oh, u16* __restrict__ ol)
{
  __shared__ u16 Kh[64*128], Kl[64*128];
  __shared__ u16 Vh[128*64], Vl[128*64];
  __shared__ u16 Ph[4*16*64], Pl[4*16*64];
  const int bx = blockIdx.x, h = blockIdx.y, b = blockIdx.z;
  const int hkv = h >> 2;
  const int lane = threadIdx.x & 63, wave = threadIdx.x >> 6;
  const int fr = lane & 15, fg = lane >> 4;
  const u16* qbh = qrh + ((size_t)(b*NHEAD + h)*S_LEN)*DHEAD;
  const u16* qbl = qrl + ((size_t)(b*NHEAD + h)*S_LEN)*DHEAD;
  const u16* kbh = krh + ((size_t)(b*NKVH + hkv)*S_LEN)*DHEAD;
  const u16* kbl = krl + ((size_t)(b*NKVH + hkv)*S_LEN)*DHEAD;
  const u16* vbh = vth + ((size_t)(b*NKVH + hkv)*DHEAD)*S_LEN;
  const u16* vbl = vtl + ((size_t)(b*NKVH + hkv)*DHEAD)*S_LEN;
  const float scl = 0.08838834764831845f;

  for (int it = 0; it < 2; it++) {
    const int qt = it ? (15 - bx) : bx;
    const int q0 = qt * 64;
    f16x8 aqh[4], aql[4];
    {
      const size_t qrow = (size_t)(q0 + wave*16 + fr)*DHEAD;
      #pragma unroll
      for (int kk = 0; kk < 4; kk++) {
        aqh[kk] = *(const f16x8*)&qbh[qrow + kk*32 + fg*8];
        aql[kk] = *(const f16x8*)&qbl[qrow + kk*32 + fg*8];
      }
    }
    f32x4 o0[8] = {}, o1[8] = {};
    float mrow[4] = {-1e30f,-1e30f,-1e30f,-1e30f};
    float lrow[4] = {0.f,0.f,0.f,0.f};
    for (int jt = 0; jt <= qt; jt++) {
      const int j0 = jt * 64;
      #pragma unroll
      for (int p = 0; p < 4; p++) {
        const int ck = p*4 + wave;
        gload_lds16(kbh + (size_t)(j0 + ck*4 + (lane>>4))*DHEAD + (lane&15)*8, &Kh[ck*512]);
        gload_lds16(kbl + (size_t)(j0 + ck*4 + (lane>>4))*DHEAD + (lane&15)*8, &Kl[ck*512]);
        gload_lds16(vbh + (size_t)(ck*8 + (lane>>3))*S_LEN + j0 + (lane&7)*8, &Vh[ck*512]);
        gload_lds16(vbl + (size_t)(ck*8 + (lane>>3))*S_LEN + j0 + (lane&7)*8, &Vl[ck*512]);
      }
      __syncthreads();
      f32x4 s0[4] = {}, s1[4] = {};
      #pragma unroll
      for (int kk = 0; kk < 4; kk++) {
        const int ko = kk*32 + fg*8;
        #pragma unroll
        for (int n = 0; n < 4; n++) {
          f16x8 bh_ = *(const f16x8*)&Kh[(n*16 + fr)*128 + ko];
          f16x8 bl_ = *(const f16x8*)&Kl[(n*16 + fr)*128 + ko];
          s0[n] = __builtin_amdgcn_mfma_f32_16x16x32_f16(aqh[kk], bh_, s0[n], 0,0,0);
          s1[n] = __builtin_amdgcn_mfma_f32_16x16x32_f16(aqh[kk], bl_, s1[n], 0,0,0);
          s1[n] = __builtin_amdgcn_mfma_f32_16x16x32_f16(aql[kk], bh_, s1[n], 0,0,0);
        }
      }
      const int rb = q0 + wave*16 + fg*4;
      float pv[4][4];
      #pragma unroll
      for (int n = 0; n < 4; n++)
        #pragma unroll
        for (int j = 0; j < 4; j++) {
          float v = (s0[n][j] + s1[n][j]*(1.0f/2048.0f)) * scl;
          if (j0 + n*16 + fr > rb + j) v = -1e30f;
          pv[n][j] = v;
        }
      float alpha[4];
      #pragma unroll
      for (int j = 0; j < 4; j++) {
        float mx = fmaxf(fmaxf(pv[0][j], pv[1][j]), fmaxf(pv[2][j], pv[3][j]));
        #pragma unroll
        for (int d = 1; d < 16; d <<= 1) mx = fmaxf(mx, __shfl_xor(mx, d, 64));
        float mnew = fmaxf(mrow[j], mx);
        alpha[j] = __expf(mrow[j] - mnew);
        mrow[j] = mnew;
      }
      float rsum[4] = {0.f,0.f,0.f,0.f};
      #pragma unroll
      for (int n = 0; n < 4; n++)
        #pragma unroll
        for (int j = 0; j < 4; j++) {
          float p = __expf(pv[n][j] - mrow[j]);
          pv[n][j] = p;
          rsum[j] += p;
        }
      #pragma unroll
      for (int j = 0; j < 4; j++) {
        #pragma unroll
        for (int d = 1; d < 16; d <<= 1) rsum[j] += __shfl_xor(rsum[j], d, 64);
        lrow[j] = lrow[j]*alpha[j] + rsum[j];
      }
      #pragma unroll
      for (int n2 = 0; n2 < 8; n2++)
        #pragma unroll
        for (int j = 0; j < 4; j++) { o0[n2][j] *= alpha[j]; o1[n2][j] *= alpha[j]; }
      #pragma unroll
      for (int n = 0; n < 4; n++)
        #pragma unroll
        for (int j = 0; j < 4; j++) {
          u16 hh, ll; split2(pv[n][j], hh, ll);
          Ph[wave*1024 + (fg*4 + j)*64 + n*16 + fr] = hh;
          Pl[wave*1024 + (fg*4 + j)*64 + n*16 + fr] = ll;
        }
      __syncthreads();
      #pragma unroll
      for (int kk = 0; kk < 2; kk++) {
        const int ko = kk*32 + fg*8;
        f16x8 ah_ = *(const f16x8*)&Ph[wave*1024 + fr*64 + ko];
        f16x8 al_ = *(const f16x8*)&Pl[wave*1024 + fr*64 + ko];
        #pragma unroll
        for (int n2 = 0; n2 < 8; n2++) {
          f16x8 vh_ = *(const f16x8*)&Vh[(n2*16 + fr)*64 + ko];
          f16x8 vl_ = *(const f16x8*)&Vl[(n2*16 + fr)*64 + ko];
          o0[n2] = __builtin_amdgcn_mfma_f32_16x16x32_f16(ah_, vh_, o0[n2], 0,0,0);
          o1[n2] = __builtin_amdgcn_mfma_f32_16x16x32_f16(ah_, vl_, o1[n2], 0,0,0);
          o1[n2] = __builtin_amdgcn_mfma_f32_16x16x32_f16(al_, vh_, o1[n2], 0,0,0);
        }
      }
      __syncthreads();
    }
    float inv[4];
    #pragma unroll
    for (int j = 0; j < 4; j++) inv[j] = 1.0f / lrow[j];
    #pragma unroll
    for (int n2 = 0; n2 < 8; n2++)
      #pragma unroll
      for (int j = 0; j < 4; j++) {
        int s = q0 + wave*16 + fg*4 + j;
        size_t idx = ((size_t)(b*S_LEN + s))*H_DIM + h*DHEAD + n2*16 + fr;
        float val = (o0[n2][j] + o1[n2][j]*(1.0f/2048.0f)) * inv[j];
        u16 hh, ll; split2(val, hh, ll);
        oh[idx] = hh; ol[idx] = ll;
      }
  }
}

// ---------------- router: 256 thr / 4 waves; fused ln2 tok write (wave 0) + 4 logits per wave ----------------
__global__ __launch_bounds__(256) void router_kernel(
    const float* __restrict__ resid, const float* __restrict__ ln2w,
    const float* __restrict__ gw, int* __restrict__ ids, float* __restrict__ wts,
    int* __restrict__ counts, u16* __restrict__ tok)
{
  __shared__ float lgs[NEXP];
  const int t = blockIdx.x, tid = threadIdx.x;
  const int lane = tid & 63, wave = tid >> 6;
  const float* x = resid + (size_t)t * H_DIM;
  float xv[32];
  float ss = 0.f;
  #pragma unroll
  for (int p = 0; p < 8; p++) {
    float4 v  = *(const float4*)&x[p*256 + lane*4];
    float4 lw = *(const float4*)&ln2w[p*256 + lane*4];
    ss += v.x*v.x + v.y*v.y + v.z*v.z + v.w*v.w;
    xv[p*4+0] = v.x*lw.x; xv[p*4+1] = v.y*lw.y; xv[p*4+2] = v.z*lw.z; xv[p*4+3] = v.w*lw.w;
  }
  #pragma unroll
  for (int d = 1; d < 64; d <<= 1) ss += __shfl_xor(ss, d, 64);
  const float rinv = rsqrtf(ss * (1.0f/H_DIM) + EPSF);
  // fused ln2 output: wave 0 holds the full row; write tok f16 while other waves compute logits
  if (wave == 0) {
    u16* tokrow = tok + (size_t)t * H_DIM;
    #pragma unroll
    for (int p = 0; p < 8; p++) {
      u32 lo = (u32)f2h(xv[p*4+0]*rinv) | ((u32)f2h(xv[p*4+1]*rinv) << 16);
      u32 hi = (u32)f2h(xv[p*4+2]*rinv) | ((u32)f2h(xv[p*4+3]*rinv) << 16);
      *(uint2*)&tokrow[p*256 + lane*4] = make_uint2(lo, hi);
    }
  }
  #pragma unroll
  for (int i = 0; i < 4; i++) {
    const int e = wave*4 + i;
    const float* g = gw + (size_t)e * H_DIM;
    float dacc = 0.f;
    #pragma unroll
    for (int p = 0; p < 8; p++) {
      float4 gv = *(const float4*)&g[p*256 + lane*4];
      dacc += xv[p*4+0]*gv.x + xv[p*4+1]*gv.y + xv[p*4+2]*gv.z + xv[p*4+3]*gv.w;
    }
    #pragma unroll
    for (int d = 1; d < 64; d <<= 1) dacc += __shfl_xor(dacc, d, 64);
    if (lane == 0) lgs[e] = dacc * rinv;
  }
  __syncthreads();
  if (tid == 0) {
    float lg[NEXP];
    #pragma unroll
    for (int e = 0; e < NEXP; e++) lg[e] = lgs[e];
    int i0 = 0; float b0 = lg[0];
    #pragma unroll
    for (int e = 1; e < NEXP; e++) if (lg[e] > b0) { b0 = lg[e]; i0 = e; }
    int i1 = -1; float b1 = -3e38f;
    #pragma unroll
    for (int e = 0; e < NEXP; e++) if (e != i0 && lg[e] > b1) { b1 = lg[e]; i1 = e; }
    float rr = __expf(b1 - b0);
    float w0 = 1.0f / (1.0f + rr);
    ids[t*2] = i0; ids[t*2+1] = i1;
    wts[t*2] = w0; wts[t*2+1] = rr * w0;
    atomicAdd(&counts[i0], 1);
    atomicAdd(&counts[i1], 1);
  }
}

__global__ void scan_kernel(const int* __restrict__ counts, int* __restrict__ offs,
                            int* __restrict__ cursor,
                            int* __restrict__ tile_e, int* __restrict__ tile_m0)
{
  if (threadIdx.x == 0) {
    int s = 0, nt = 0;
    for (int e = 0; e < NEXP; e++) {
      offs[e] = s; cursor[e] = 0;
      int c = counts[e];
      for (int m0 = 0; m0 < c; m0 += 256) { tile_e[nt] = e; tile_m0[nt] = m0; nt++; }
      s += c;
    }
    for (; nt < 32; nt++) { tile_e[nt] = -1; tile_m0[nt] = 0; }
  }
}

__global__ __launch_bounds__(256) void scatter_kernel(
    const int* __restrict__ ids, const int* __restrict__ offs,
    int* __restrict__ cursor, int* __restrict__ list, int* __restrict__ pos)
{
  int t = blockIdx.x * 256 + threadIdx.x;
  if (t < T_TOK) {
    for (int kk = 0; kk < 2; kk++) {
      int e = ids[t*2 + kk];
      int p = atomicAdd(&cursor[e], 1);
      int i = offs[e] + p;
      list[i] = t;
      pos[t*2 + kk] = i;
    }
  }
}

// ---------------- silu_all: expert rows (0..4095) + shared rows (4096..6143) ----------------
__global__ __launch_bounds__(256) void silu_all_kernel(
    const float* __restrict__ gu_exp, u16* __restrict__ act_ex,
    const float* __restrict__ gu_sh,  u16* __restrict__ act_sh)
{
  const int rr = blockIdx.x;
  const float* g;
  u16* o;
  if (rr < 2*T_TOK) { g = gu_exp + (size_t)rr * FF2;          o = act_ex + (size_t)rr * FFE; }
  else              { g = gu_sh  + (size_t)(rr - 2*T_TOK) * FF2; o = act_sh + (size_t)(rr - 2*T_TOK) * FFE; }
  for (int c = threadIdx.x*4; c < FFE; c += 1024) {
    float4 gv = *(const float4*)&g[c];
    float4 uv = *(const float4*)&g[c + FFE];
    float s0 = gv.x / (1.0f + __expf(-gv.x)) * uv.x;
    float s1 = gv.y / (1.0f + __expf(-gv.y)) * uv.y;
    float s2 = gv.z / (1.0f + __expf(-gv.z)) * uv.z;
    float s3 = gv.w / (1.0f + __expf(-gv.w)) * uv.w;
    u32 lo = (u32)f2h(s0) | ((u32)f2h(s1) << 16);
    u32 hi = (u32)f2h(s2) | ((u32)f2h(s3) << 16);
    *(uint2*)&o[c] = make_uint2(lo, hi);
  }
}

// out = out(shared) + w0*y[p0] + w1*y[p1]   (in-place RMW on d_out)
__global__ __launch_bounds__(256) void combine_kernel(
    const float* __restrict__ y,
    const int* __restrict__ pos, const float* __restrict__ wts,
    float* __restrict__ out)
{
  const int t = blockIdx.x;
  const int p0 = pos[t*2], p1 = pos[t*2+1];
  const float w0 = wts[t*2] * RSF_C, w1 = wts[t*2+1] * RSF_C;
  const int c = threadIdx.x * 8;
  #pragma unroll
  for (int q = 0; q < 2; q++) {
    const int cc = c + q*4;
    float4 s  = *(const float4*)&out[(size_t)t*H_DIM + cc];
    float4 a  = *(const float4*)&y[(size_t)p0*H_DIM + cc];
    float4 bb = *(const float4*)&y[(size_t)p1*H_DIM + cc];
    float4 r;
    r.x = s.x + w0*a.x + w1*bb.x;
    r.y = s.y + w0*a.y + w1*bb.y;
    r.z = s.z + w0*a.z + w1*bb.z;
    r.w = s.w + w0*a.w + w1*bb.w;
    *(float4*)&out[(size_t)t*H_DIM + cc] = r;
  }
}

extern "C" void kernel_launch(void* const* d_in, const int* in_sizes, int n_in,
                              void* d_out, int out_size, void* d_ws, size_t ws_size,
                              hipStream_t stream)
{
  (void)in_sizes; (void)n_in; (void)out_size;
  const float* hidden = (const float*)d_in[0];
  const float* cosb   = (const float*)d_in[1];
  const float* sinb   = (const float*)d_in[2];
  const float* ln1w   = (const float*)d_in[3];
  const float* ln2w   = (const float*)d_in[4];
  const float* qnw    = (const float*)d_in[5];
  const float* knw    = (const float*)d_in[6];
  const float* wq     = (const float*)d_in[7];
  const float* wk     = (const float*)d_in[8];
  const float* wv     = (const float*)d_in[9];
  const float* wo     = (const float*)d_in[10];
  const float* gw     = (const float*)d_in[11];
  const float* egu    = (const float*)d_in[12];
  const float* edn    = (const float*)d_in[13];
  const float* sgu    = (const float*)d_in[14];
  const float* sdn    = (const float*)d_in[15];
  float* out_hidden = (float*)d_out;
  float* resid = (float*)d_out + (size_t)T_TOK * H_DIM;

  char* ws = (char*)d_ws;
  // ---- phase A (pre-router) ----
  constexpr size_t OFF_XH    = 0;
  constexpr size_t OFF_XL    = 8388608;
  constexpr size_t OFF_WQKVH = 16777216;
  constexpr size_t OFF_WQKVL = 29360128;
  constexpr size_t OFF_WOH   = 41943040;
  constexpr size_t OFF_WOL   = 50331648;
  constexpr size_t OFF_QKV   = 58720256;   // 25,165,824 f32 [2048][3072]
  constexpr size_t OFF_QRH = 16777216, OFF_QRL = 25165824;
  constexpr size_t OFF_KRH = 33554432, OFF_KRL = 35651584;
  constexpr size_t OFF_VTH = 37748736, OFF_VTL = 39845888;
  constexpr size_t OFF_OH = 58720256, OFF_OL = 67108864;
  // ---- phase B (post-router) ----
  constexpr size_t OFF_GUE = 0;            // gu_exp 46,137,344 ; later y_exp 33,554,432
  constexpr size_t OFF_TOK = 63963136;     // 8,388,608
  constexpr size_t OFF_ACE = 72351744;     // act_ex (4096+256)x1408x2 = 12,255,232
  constexpr size_t OFF_GUS = 84606976;     // 23,068,672
  constexpr size_t OFF_ACS = 107675648;    // 5,767,168
  constexpr size_t OFF_SGUT= 113442816;    // 11,534,336
  constexpr size_t OFF_SDNT= 124977152;    // 5,767,168
  constexpr size_t OFF_IDS = 130744320;
  constexpr size_t OFF_WTS = OFF_IDS + 16384;
  constexpr size_t OFF_POS = OFF_WTS + 16384;
  constexpr size_t OFF_LST = OFF_POS + 16384;
  constexpr size_t OFF_CNT = OFF_LST + 16384;
  constexpr size_t OFF_OFS = OFF_CNT + 64;
  constexpr size_t OFF_CUR = OFF_OFS + 64;
  constexpr size_t OFF_TE  = OFF_CUR + 64;
  constexpr size_t OFF_TM  = OFF_TE + 128;
  constexpr size_t WS_NEED = OFF_TM + 128;
  if (ws_size < WS_NEED) return;

  u16* xh     = (u16*)(ws + OFF_XH);
  u16* xl     = (u16*)(ws + OFF_XL);
  u16* wqkvh  = (u16*)(ws + OFF_WQKVH);
  u16* wqkvl  = (u16*)(ws + OFF_WQKVL);
  u16* woh    = (u16*)(ws + OFF_WOH);
  u16* wol    = (u16*)(ws + OFF_WOL);
  float* qkv  = (float*)(ws + OFF_QKV);
  u16* q_rh = (u16*)(ws + OFF_QRH);
  u16* q_rl = (u16*)(ws + OFF_QRL);
  u16* k_rh = (u16*)(ws + OFF_KRH);
  u16* k_rl = (u16*)(ws + OFF_KRL);
  u16* v_th = (u16*)(ws + OFF_VTH);
  u16* v_tl = (u16*)(ws + OFF_VTL);
  u16* o_h  = (u16*)(ws + OFF_OH);
  u16* o_l  = (u16*)(ws + OFF_OL);
  float* gu_exp = (float*)(ws + OFF_GUE);
  float* y_exp  = (float*)(ws + OFF_GUE);
  u16* tok      = (u16*)(ws + OFF_TOK);
  u16* act_ex   = (u16*)(ws + OFF_ACE);
  float* gu_sh  = (float*)(ws + OFF_GUS);
  u16* act_sh   = (u16*)(ws + OFF_ACS);
  u16* sgut     = (u16*)(ws + OFF_SGUT);
  u16* sdnt     = (u16*)(ws + OFF_SDNT);
  int* ids    = (int*)(ws + OFF_IDS);
  float* wts  = (float*)(ws + OFF_WTS);
  int* pos    = (int*)(ws + OFF_POS);
  int* list   = (int*)(ws + OFF_LST);
  int* counts = (int*)(ws + OFF_CNT);
  int* offs   = (int*)(ws + OFF_OFS);
  int* cursor = (int*)(ws + OFF_CUR);
  int* tile_e = (int*)(ws + OFF_TE);
  int* tile_m0= (int*)(ws + OFF_TM);

  hipMemsetAsync(counts, 0, 64, stream);

  // ---- prep: all weight transpose/split jobs in ONE launch ----
  tsplit_all_kernel<<<dim3(44,32,6), 256, 0, stream>>>(wq, wk, wv, wo, sgu, sdn,
                                                       wqkvh, wqkvl, woh, wol, sgut, sdnt);

  // ---- pre-router chain (f16 hi/lo precision) ----
  rmsnorm_kernel<<<T_TOK, 256, 0, stream>>>(hidden, ln1w, xh, xl);
  gemm3b_kernel<<<dim3(24,16), 256, 0, stream>>>(xh, xl, H_DIM, wqkvh, wqkvl, 2048, qkv, 3072, nullptr, H_DIM);
  rope_kernel<<<(T_TOK*24)/4, 256, 0, stream>>>(qkv, cosb, sinb, qnw, knw,
                                                q_rh, q_rl, k_rh, k_rl, v_th, v_tl);
  attn_kernel<<<dim3(8, NHEAD, NB), 256, 0, stream>>>(q_rh, q_rl, k_rh, k_rl, v_th, v_tl, o_h, o_l);
  gemm3b_kernel<<<dim3(16,16), 256, 0, stream>>>(o_h, o_l, H_DIM, woh, wol, 2048, resid, H_DIM, hidden, H_DIM);

  // ---- router (fused ln2 -> tok, 4-wave) ----
  router_kernel<<<T_TOK, 256, 0, stream>>>(resid, ln2w, gw, ids, wts, counts, tok);
  scan_kernel<<<1, 64, 0, stream>>>(counts, offs, cursor, tile_e, tile_m0);
  scatter_kernel<<<8, 256, 0, stream>>>(ids, offs, cursor, list, pos);

  // ---- MoE: merged up (indirect A from tok via list -- no gather), merged silu, merged down, combine ----
  gemm_up_all_kernel<<<dim3(44,1,40), 256, 0, stream>>>(list, egu, gu_exp,
                                                        counts, offs, tile_e, tile_m0,
                                                        tok, sgut, gu_sh);
  silu_all_kernel<<<3*T_TOK, 256, 0, stream>>>(gu_exp, act_ex, gu_sh, act_sh);
  gemm_dn_all_kernel<<<dim3(32,1,40), 256, 0, stream>>>(act_ex, edn, y_exp,
                                                        counts, offs, tile_e, tile_m0,
                                                        act_sh, sdnt, out_hidden);
  combine_kernel<<<T_TOK, 256, 0, stream>>>(y_exp, pos, wts, out_hidden);
}

// Round 25
// 661.814 us; speedup vs baseline: 1.2278x; 1.0999x over previous
//
#include <hip/hip_runtime.h>
#include <stdint.h>

typedef unsigned short u16;
typedef unsigned int   u32;
typedef __attribute__((ext_vector_type(4))) float     f32x4;
typedef __attribute__((ext_vector_type(8))) _Float16  f16x8;

#define S_LEN 1024
#define NB    2
#define H_DIM 2048
#define T_TOK 2048
#define NHEAD 16
#define NKVH  4
#define DHEAD 128
#define NEXP  16
#define FFE   1408
#define FF2   2816
#define EPSF  1e-5f
#define RSF_C 1.0f

// ---- f32 <-> f16 helpers (scaled hi/lo split: x ~= hi + lo/2048) ----
__device__ __forceinline__ u16 f2h(float f){
  _Float16 h = (_Float16)f;
  return __builtin_bit_cast(unsigned short, h);
}
__device__ __forceinline__ void split2(float f, u16& hi, u16& lo){
  _Float16 h = (_Float16)f;
  hi = __builtin_bit_cast(unsigned short, h);
  _Float16 l = (_Float16)((f - (float)h) * 2048.0f);
  lo = __builtin_bit_cast(unsigned short, l);
}
__device__ __forceinline__ void gload_lds16(const void* g, void* l){
  __builtin_amdgcn_global_load_lds((const __attribute__((address_space(1))) void*)g,
                                   (__attribute__((address_space(3))) void*)l, 16, 0, 0);
}
__device__ __forceinline__ uint4 pack8(const u16* p){
  return make_uint4((u32)p[0] | ((u32)p[1]<<16), (u32)p[2] | ((u32)p[3]<<16),
                    (u32)p[4] | ((u32)p[5]<<16), (u32)p[6] | ((u32)p[7]<<16));
}

// ---------------- tsplit_all: all six weight transpose/split jobs in one launch ----------------
// z: 0=wq 1=wk 2=wv 3=wo (dual) 4=sgu 5=sdn (single). grid (44,32,6); oversized blocks exit early.
__global__ __launch_bounds__(256) void tsplit_all_kernel(
    const float* __restrict__ wq, const float* __restrict__ wk,
    const float* __restrict__ wv, const float* __restrict__ wo,
    const float* __restrict__ sgu, const float* __restrict__ sdn,
    u16* __restrict__ wqkvh, u16* __restrict__ wqkvl,
    u16* __restrict__ woh,  u16* __restrict__ wol,
    u16* __restrict__ sgut, u16* __restrict__ sdnt)
{
  const int z = blockIdx.z;
  const float* in; int ldn; u16* outh; u16* outl; int ldk, nx, ny; bool dual;
  switch (z) {
    case 0:  in=wq;  ldn=2048; outh=wqkvh;              outl=wqkvl;              ldk=2048; nx=32; ny=32; dual=true;  break;
    case 1:  in=wk;  ldn=512;  outh=wqkvh+2048*2048;    outl=wqkvl+2048*2048;    ldk=2048; nx=8;  ny=32; dual=true;  break;
    case 2:  in=wv;  ldn=512;  outh=wqkvh+2560*2048;    outl=wqkvl+2560*2048;    ldk=2048; nx=8;  ny=32; dual=true;  break;
    case 3:  in=wo;  ldn=2048; outh=woh;                outl=wol;                ldk=2048; nx=32; ny=32; dual=true;  break;
    case 4:  in=sgu; ldn=2816; outh=sgut;               outl=nullptr;            ldk=2048; nx=44; ny=32; dual=false; break;
    default: in=sdn; ldn=2048; outh=sdnt;               outl=nullptr;            ldk=1408; nx=32; ny=22; dual=false; break;
  }
  if ((int)blockIdx.x >= nx || (int)blockIdx.y >= ny) return;
  __shared__ float tile[64][65];
  const int n0 = blockIdx.x * 64, k0 = blockIdx.y * 64;
  const int tid = threadIdx.x;
  const int tr = tid >> 4, tc = (tid & 15) * 4;
  #pragma unroll
  for (int i = 0; i < 4; i++) {
    float4 v = *(const float4*)&in[(size_t)(k0 + tr + i*16) * ldn + (n0 + tc)];
    tile[tr + i*16][tc+0] = v.x; tile[tr + i*16][tc+1] = v.y;
    tile[tr + i*16][tc+2] = v.z; tile[tr + i*16][tc+3] = v.w;
  }
  __syncthreads();
  const int n = tid >> 2, kg = (tid & 3) * 16;
  u16 hb[16], lb[16];
  #pragma unroll
  for (int j = 0; j < 16; j++) {
    float f = tile[kg + j][n];
    if (dual) split2(f, hb[j], lb[j]); else hb[j] = f2h(f);
  }
  u16* dh = &outh[(size_t)(n0 + n) * ldk + k0 + kg];
  *(uint4*)dh       = pack8(hb);
  *(uint4*)(dh + 8) = pack8(hb + 8);
  if (dual) {
    u16* dl = &outl[(size_t)(n0 + n) * ldk + k0 + kg];
    *(uint4*)dl       = pack8(lb);
    *(uint4*)(dl + 8) = pack8(lb + 8);
  }
}

// ---------------- RMSNorm: f32 in -> f16 hi (+optional scaled lo) ----------------
__global__ __launch_bounds__(256) void rmsnorm_kernel(
    const float* __restrict__ in, const float* __restrict__ w,
    u16* __restrict__ outh, u16* __restrict__ outl)
{
  __shared__ float red[4];
  const int t = blockIdx.x, tid = threadIdx.x;
  const int lane = tid & 63, wave = tid >> 6;
  const float* x = in + (size_t)t * H_DIM;
  const int c = tid * 8;
  float4 v0 = *(const float4*)&x[c];
  float4 v1 = *(const float4*)&x[c + 4];
  float ss = v0.x*v0.x + v0.y*v0.y + v0.z*v0.z + v0.w*v0.w
           + v1.x*v1.x + v1.y*v1.y + v1.z*v1.z + v1.w*v1.w;
  #pragma unroll
  for (int d = 1; d < 64; d <<= 1) ss += __shfl_xor(ss, d, 64);
  if (lane == 0) red[wave] = ss;
  __syncthreads();
  float rinv = rsqrtf((red[0]+red[1]+red[2]+red[3]) * (1.0f/H_DIM) + EPSF);
  float4 w0 = *(const float4*)&w[c];
  float4 w1 = *(const float4*)&w[c + 4];
  float vals[8] = { v0.x*rinv*w0.x, v0.y*rinv*w0.y, v0.z*rinv*w0.z, v0.w*rinv*w0.w,
                    v1.x*rinv*w1.x, v1.y*rinv*w1.y, v1.z*rinv*w1.z, v1.w*rinv*w1.w };
  u16 hb[8], lb[8];
  #pragma unroll
  for (int j = 0; j < 8; j++) split2(vals[j], hb[j], lb[j]);
  *(uint4*)&outh[(size_t)t * H_DIM + c] = pack8(hb);
  if (outl) *(uint4*)&outl[(size_t)t * H_DIM + c] = pack8(lb);
}

// ---------------- gemm3b: C(f32) = (Ah+Al/2048) @ (Bh+Bl/2048)^T; 128x128, BK=64, swizzled LDS ----------------
__global__ __launch_bounds__(256) void gemm3b_kernel(
    const u16* __restrict__ Ah, const u16* __restrict__ Al, int lda,
    const u16* __restrict__ Bh, const u16* __restrict__ Bl, int ldb,
    float* __restrict__ C, int ldc,
    const float* __restrict__ addsrc, int K)
{
  __shared__ u16 Ash[128*64], Asl[128*64];
  __shared__ u16 Bsh[128*64], Bsl[128*64];
  const int tid = threadIdx.x, lane = tid & 63, wave = tid >> 6;
  const int m0 = blockIdx.y * 128, n0 = blockIdx.x * 128;
  const int wm = (wave >> 1) * 64, wn = (wave & 1) * 64;
  const int arow = lane >> 3;
  const int acol = ((lane & 7) ^ arow) * 8;
  f32x4 acc0[4][4] = {}, acc1[4][4] = {};
  for (int k0 = 0; k0 < K; k0 += 64) {
    #pragma unroll
    for (int g = 0; g < 4; g++) {
      const int rb = wave*32 + g*8;
      gload_lds16(Ah + (size_t)(m0 + rb + arow)*lda + k0 + acol, &Ash[rb*64]);
      gload_lds16(Al + (size_t)(m0 + rb + arow)*lda + k0 + acol, &Asl[rb*64]);
      gload_lds16(Bh + (size_t)(n0 + rb + arow)*ldb + k0 + acol, &Bsh[rb*64]);
      gload_lds16(Bl + (size_t)(n0 + rb + arow)*ldb + k0 + acol, &Bsl[rb*64]);
    }
    asm volatile("s_waitcnt vmcnt(0) lgkmcnt(0)" ::: "memory");
    __syncthreads();
    const int fr = lane & 15, fg = lane >> 4;
    #pragma unroll
    for (int kk = 0; kk < 2; kk++) {
      const int cb = fg + kk*4;
      f16x8 ah[4], al[4];
      #pragma unroll
      for (int m = 0; m < 4; m++) {
        const int r = wm + m*16 + fr;
        const int s = (cb ^ (r & 7)) * 8;
        ah[m] = *(const f16x8*)&Ash[r*64 + s];
        al[m] = *(const f16x8*)&Asl[r*64 + s];
      }
      #pragma unroll
      for (int n = 0; n < 4; n++) {
        const int r = wn + n*16 + fr;
        const int s = (cb ^ (r & 7)) * 8;
        f16x8 bh_ = *(const f16x8*)&Bsh[r*64 + s];
        f16x8 bl_ = *(const f16x8*)&Bsl[r*64 + s];
        #pragma unroll
        for (int m = 0; m < 4; m++) {
          acc0[m][n] = __builtin_amdgcn_mfma_f32_16x16x32_f16(ah[m], bh_, acc0[m][n], 0,0,0);
          acc1[m][n] = __builtin_amdgcn_mfma_f32_16x16x32_f16(ah[m], bl_, acc1[m][n], 0,0,0);
          acc1[m][n] = __builtin_amdgcn_mfma_f32_16x16x32_f16(al[m], bh_, acc1[m][n], 0,0,0);
        }
      }
    }
    __syncthreads();
  }
  const int cr = (lane >> 4) * 4, cc = lane & 15;
  #pragma unroll
  for (int m = 0; m < 4; m++)
    #pragma unroll
    for (int n = 0; n < 4; n++)
      #pragma unroll
      for (int j = 0; j < 4; j++) {
        int r = m0 + wm + m*16 + cr + j;
        size_t idx = (size_t)r * ldc + (n0 + wn + n*16 + cc);
        float v = acc0[m][n][j] + acc1[m][n][j] * (1.0f/2048.0f);
        if (addsrc) v += addsrc[idx];
        C[idx] = v;
      }
}

// ---------------- gemm3b96: same as gemm3b but 128x96 tile (grid.x * 96 n-strips, 512 blocks for qkv) ----------------
__global__ __launch_bounds__(256) void gemm3b96_kernel(
    const u16* __restrict__ Ah, const u16* __restrict__ Al, int lda,
    const u16* __restrict__ Bh, const u16* __restrict__ Bl, int ldb,
    float* __restrict__ C, int ldc, int K)
{
  __shared__ u16 Ash[128*64], Asl[128*64];
  __shared__ u16 Bsh[96*64], Bsl[96*64];
  const int tid = threadIdx.x, lane = tid & 63, wave = tid >> 6;
  const int m0 = blockIdx.y * 128, n0 = blockIdx.x * 96;
  const int wm = (wave >> 1) * 64, wn = (wave & 1) * 48;
  const int arow = lane >> 3;
  const int acol = ((lane & 7) ^ arow) * 8;
  f32x4 acc0[4][3] = {}, acc1[4][3] = {};
  for (int k0 = 0; k0 < K; k0 += 64) {
    #pragma unroll
    for (int g = 0; g < 4; g++) {
      const int rb = wave*32 + g*8;
      gload_lds16(Ah + (size_t)(m0 + rb + arow)*lda + k0 + acol, &Ash[rb*64]);
      gload_lds16(Al + (size_t)(m0 + rb + arow)*lda + k0 + acol, &Asl[rb*64]);
    }
    #pragma unroll
    for (int g = 0; g < 3; g++) {
      const int rb = wave*24 + g*8;
      gload_lds16(Bh + (size_t)(n0 + rb + arow)*ldb + k0 + acol, &Bsh[rb*64]);
      gload_lds16(Bl + (size_t)(n0 + rb + arow)*ldb + k0 + acol, &Bsl[rb*64]);
    }
    asm volatile("s_waitcnt vmcnt(0) lgkmcnt(0)" ::: "memory");
    __syncthreads();
    const int fr = lane & 15, fg = lane >> 4;
    #pragma unroll
    for (int kk = 0; kk < 2; kk++) {
      const int cb = fg + kk*4;
      f16x8 ah[4], al[4];
      #pragma unroll
      for (int m = 0; m < 4; m++) {
        const int r = wm + m*16 + fr;
        const int s = (cb ^ (r & 7)) * 8;
        ah[m] = *(const f16x8*)&Ash[r*64 + s];
        al[m] = *(const f16x8*)&Asl[r*64 + s];
      }
      #pragma unroll
      for (int n = 0; n < 3; n++) {
        const int r = wn + n*16 + fr;
        const int s = (cb ^ (r & 7)) * 8;
        f16x8 bh_ = *(const f16x8*)&Bsh[r*64 + s];
        f16x8 bl_ = *(const f16x8*)&Bsl[r*64 + s];
        #pragma unroll
        for (int m = 0; m < 4; m++) {
          acc0[m][n] = __builtin_amdgcn_mfma_f32_16x16x32_f16(ah[m], bh_, acc0[m][n], 0,0,0);
          acc1[m][n] = __builtin_amdgcn_mfma_f32_16x16x32_f16(ah[m], bl_, acc1[m][n], 0,0,0);
          acc1[m][n] = __builtin_amdgcn_mfma_f32_16x16x32_f16(al[m], bh_, acc1[m][n], 0,0,0);
        }
      }
    }
    __syncthreads();
  }
  const int cr = (lane >> 4) * 4, cc = lane & 15;
  #pragma unroll
  for (int m = 0; m < 4; m++)
    #pragma unroll
    for (int n = 0; n < 3; n++)
      #pragma unroll
      for (int j = 0; j < 4; j++) {
        int r = m0 + wm + m*16 + cr + j;
        size_t idx = (size_t)r * ldc + (n0 + wn + n*16 + cc);
        C[idx] = acc0[m][n][j] + acc1[m][n][j] * (1.0f/2048.0f);
      }
}

// ---------------- gemm_up_all: expert up (tile queue, indirect A via list, f32 B) + shared up (dense, u16 B) ----------------
// grid (44, 1, 40): z<32 -> expert tile z; z>=32 -> shared m-tile (z-32). M=256 x N=64, BK=64.
__global__ __launch_bounds__(256) void gemm_up_all_kernel(
    const int* __restrict__ list, const float* __restrict__ egu, float* __restrict__ gu_exp,
    const int* __restrict__ counts, const int* __restrict__ offs,
    const int* __restrict__ tile_e, const int* __restrict__ tile_m0,
    const u16* __restrict__ tok, const u16* __restrict__ sgut, float* __restrict__ gu_sh)
{
  __shared__ u16 As[256*64];
  __shared__ u16 Bs[64*64];
  const int z = blockIdx.z;
  const int tid = threadIdx.x, lane = tid & 63, wave = tid >> 6;
  const int n0 = blockIdx.x * 64;
  const int wm = wave * 64;
  const int arow = lane >> 3;
  const int acol = ((lane & 7) ^ arow) * 8;
  const int fr = lane & 15, fg = lane >> 4;
  const int cr = (lane >> 4) * 4, cc = lane & 15;

  if (z < 32) {
    const int e = tile_e[z];
    if (e < 0) return;
    const int m0 = tile_m0[z];
    const int cnt = counts[e];
    const int off = offs[e];
    const float* B = egu + (size_t)e * H_DIM * FF2;
    float* C = gu_exp + (size_t)off * FF2;
    const u16* arp[8];
    #pragma unroll
    for (int g = 0; g < 8; g++) {
      int idx = off + m0 + wm + g*8 + arow;
      if (idx > 2*T_TOK - 1) idx = 2*T_TOK - 1;
      arp[g] = tok + (size_t)list[idx] * H_DIM + acol;
    }
    const int bn  = tid & 63;
    const int bkb = tid >> 6;
    const int bs0 = bn*64 + (((bkb*2)     ^ (bn & 7)) * 8);
    const int bs1 = bn*64 + (((bkb*2 + 1) ^ (bn & 7)) * 8);
    f32x4 acc[4][4] = {};
    for (int k0 = 0; k0 < H_DIM; k0 += 64) {
      #pragma unroll
      for (int g = 0; g < 8; g++)
        gload_lds16(arp[g] + k0, &As[(wm + g*8)*64]);
      {
        const float* gb = B + (size_t)(k0 + bkb*16) * FF2 + (n0 + bn);
        float f[16];
        #pragma unroll
        for (int j = 0; j < 16; j++) f[j] = gb[(size_t)j * FF2];
        u32 pk[8];
        #pragma unroll
        for (int j = 0; j < 8; j++)
          pk[j] = __builtin_bit_cast(u32, __builtin_amdgcn_cvt_pkrtz(f[2*j], f[2*j+1]));
        *(uint4*)&Bs[bs0] = make_uint4(pk[0], pk[1], pk[2], pk[3]);
        *(uint4*)&Bs[bs1] = make_uint4(pk[4], pk[5], pk[6], pk[7]);
      }
      asm volatile("s_waitcnt vmcnt(0) lgkmcnt(0)" ::: "memory");
      __syncthreads();
      #pragma unroll
      for (int kk = 0; kk < 2; kk++) {
        const int cb = fg + kk*4;
        f16x8 a[4], b[4];
        #pragma unroll
        for (int m = 0; m < 4; m++) {
          const int r = wm + m*16 + fr;
          a[m] = *(const f16x8*)&As[r*64 + ((cb ^ (r & 7)) * 8)];
        }
        #pragma unroll
        for (int n = 0; n < 4; n++) {
          const int r = n*16 + fr;
          b[n] = *(const f16x8*)&Bs[r*64 + ((cb ^ (r & 7)) * 8)];
        }
        #pragma unroll
        for (int n = 0; n < 4; n++)
          #pragma unroll
          for (int m = 0; m < 4; m++)
            acc[m][n] = __builtin_amdgcn_mfma_f32_16x16x32_f16(a[m], b[n], acc[m][n], 0,0,0);
      }
      __syncthreads();
    }
    #pragma unroll
    for (int m = 0; m < 4; m++)
      #pragma unroll
      for (int n = 0; n < 4; n++)
        #pragma unroll
        for (int j = 0; j < 4; j++) {
          int r = m0 + wm + m*16 + cr + j;
          if (r < cnt) C[(size_t)r * FF2 + (n0 + n*16 + cc)] = acc[m][n][j];
        }
  } else {
    const int m0 = (z - 32) * 256;
    f32x4 acc[4][4] = {};
    for (int k0 = 0; k0 < H_DIM; k0 += 64) {
      #pragma unroll
      for (int g = 0; g < 8; g++)
        gload_lds16(tok + (size_t)(m0 + wm + g*8 + arow)*H_DIM + k0 + acol,
                    &As[(wm + g*8)*64]);
      #pragma unroll
      for (int g = 0; g < 2; g++)
        gload_lds16(sgut + (size_t)(n0 + wave*16 + g*8 + arow)*H_DIM + k0 + acol,
                    &Bs[(wave*16 + g*8)*64]);
      asm volatile("s_waitcnt vmcnt(0) lgkmcnt(0)" ::: "memory");
      __syncthreads();
      #pragma unroll
      for (int kk = 0; kk < 2; kk++) {
        const int cb = fg + kk*4;
        f16x8 a[4], b[4];
        #pragma unroll
        for (int m = 0; m < 4; m++) {
          const int r = wm + m*16 + fr;
          a[m] = *(const f16x8*)&As[r*64 + ((cb ^ (r & 7)) * 8)];
        }
        #pragma unroll
        for (int n = 0; n < 4; n++) {
          const int r = n*16 + fr;
          b[n] = *(const f16x8*)&Bs[r*64 + ((cb ^ (r & 7)) * 8)];
        }
        #pragma unroll
        for (int n = 0; n < 4; n++)
          #pragma unroll
          for (int m = 0; m < 4; m++)
            acc[m][n] = __builtin_amdgcn_mfma_f32_16x16x32_f16(a[m], b[n], acc[m][n], 0,0,0);
      }
      __syncthreads();
    }
    #pragma unroll
    for (int m = 0; m < 4; m++)
      #pragma unroll
      for (int n = 0; n < 4; n++)
        #pragma unroll
        for (int j = 0; j < 4; j++)
          gu_sh[(size_t)(m0 + wm + m*16 + cr + j) * FF2 + (n0 + n*16 + cc)] = acc[m][n][j];
  }
}

// ---------------- gemm_dn_all: expert down (tile queue, f32 B -> y_exp) + shared down (u16 B -> out) ----------------
__global__ __launch_bounds__(256) void gemm_dn_all_kernel(
    const u16* __restrict__ Aexp, const float* __restrict__ edn, float* __restrict__ y_exp,
    const int* __restrict__ counts, const int* __restrict__ offs,
    const int* __restrict__ tile_e, const int* __restrict__ tile_m0,
    const u16* __restrict__ act_sh, const u16* __restrict__ sdnt, float* __restrict__ out_sh)
{
  __shared__ u16 As[256*64];
  __shared__ u16 Bs[64*64];
  const int z = blockIdx.z;
  const int tid = threadIdx.x, lane = tid & 63, wave = tid >> 6;
  const int n0 = blockIdx.x * 64;
  const int wm = wave * 64;
  const int arow = lane >> 3;
  const int acol = ((lane & 7) ^ arow) * 8;
  const int fr = lane & 15, fg = lane >> 4;
  const int cr = (lane >> 4) * 4, cc = lane & 15;

  if (z < 32) {
    const int e = tile_e[z];
    if (e < 0) return;
    const int m0 = tile_m0[z];
    const int cnt = counts[e];
    const int off = offs[e];
    const u16* A = Aexp + (size_t)off * FFE;
    const float* B = edn + (size_t)e * FFE * H_DIM;
    float* C = y_exp + (size_t)off * H_DIM;
    const int bn  = tid & 63;
    const int bkb = tid >> 6;
    const int bs0 = bn*64 + (((bkb*2)     ^ (bn & 7)) * 8);
    const int bs1 = bn*64 + (((bkb*2 + 1) ^ (bn & 7)) * 8);
    f32x4 acc[4][4] = {};
    for (int k0 = 0; k0 < FFE; k0 += 64) {
      #pragma unroll
      for (int g = 0; g < 8; g++)
        gload_lds16(A + (size_t)(m0 + wm + g*8 + arow)*FFE + k0 + acol,
                    &As[(wm + g*8)*64]);
      {
        const float* gb = B + (size_t)(k0 + bkb*16) * H_DIM + (n0 + bn);
        float f[16];
        #pragma unroll
        for (int j = 0; j < 16; j++) f[j] = gb[(size_t)j * H_DIM];
        u32 pk[8];
        #pragma unroll
        for (int j = 0; j < 8; j++)
          pk[j] = __builtin_bit_cast(u32, __builtin_amdgcn_cvt_pkrtz(f[2*j], f[2*j+1]));
        *(uint4*)&Bs[bs0] = make_uint4(pk[0], pk[1], pk[2], pk[3]);
        *(uint4*)&Bs[bs1] = make_uint4(pk[4], pk[5], pk[6], pk[7]);
      }
      asm volatile("s_waitcnt vmcnt(0) lgkmcnt(0)" ::: "memory");
      __syncthreads();
      #pragma unroll
      for (int kk = 0; kk < 2; kk++) {
        const int cb = fg + kk*4;
        f16x8 a[4], b[4];
        #pragma unroll
        for (int m = 0; m < 4; m++) {
          const int r = wm + m*16 + fr;
          a[m] = *(const f16x8*)&As[r*64 + ((cb ^ (r & 7)) * 8)];
        }
        #pragma unroll
        for (int n = 0; n < 4; n++) {
          const int r = n*16 + fr;
          b[n] = *(const f16x8*)&Bs[r*64 + ((cb ^ (r & 7)) * 8)];
        }
        #pragma unroll
        for (int n = 0; n < 4; n++)
          #pragma unroll
          for (int m = 0; m < 4; m++)
            acc[m][n] = __builtin_amdgcn_mfma_f32_16x16x32_f16(a[m], b[n], acc[m][n], 0,0,0);
      }
      __syncthreads();
    }
    #pragma unroll
    for (int m = 0; m < 4; m++)
      #pragma unroll
      for (int n = 0; n < 4; n++)
        #pragma unroll
        for (int j = 0; j < 4; j++) {
          int r = m0 + wm + m*16 + cr + j;
          if (r < cnt) C[(size_t)r * H_DIM + (n0 + n*16 + cc)] = acc[m][n][j];
        }
  } else {
    const int m0 = (z - 32) * 256;
    f32x4 acc[4][4] = {};
    for (int k0 = 0; k0 < FFE; k0 += 64) {
      #pragma unroll
      for (int g = 0; g < 8; g++)
        gload_lds16(act_sh + (size_t)(m0 + wm + g*8 + arow)*FFE + k0 + acol,
                    &As[(wm + g*8)*64]);
      #pragma unroll
      for (int g = 0; g < 2; g++)
        gload_lds16(sdnt + (size_t)(n0 + wave*16 + g*8 + arow)*FFE + k0 + acol,
                    &Bs[(wave*16 + g*8)*64]);
      asm volatile("s_waitcnt vmcnt(0) lgkmcnt(0)" ::: "memory");
      __syncthreads();
      #pragma unroll
      for (int kk = 0; kk < 2; kk++) {
        const int cb = fg + kk*4;
        f16x8 a[4], b[4];
        #pragma unroll
        for (int m = 0; m < 4; m++) {
          const int r = wm + m*16 + fr;
          a[m] = *(const f16x8*)&As[r*64 + ((cb ^ (r & 7)) * 8)];
        }
        #pragma unroll
        for (int n = 0; n < 4; n++) {
          const int r = n*16 + fr;
          b[n] = *(const f16x8*)&Bs[r*64 + ((cb ^ (r & 7)) * 8)];
        }
        #pragma unroll
        for (int n = 0; n < 4; n++)
          #pragma unroll
          for (int m = 0; m < 4; m++)
            acc[m][n] = __builtin_amdgcn_mfma_f32_16x16x32_f16(a[m], b[n], acc[m][n], 0,0,0);
      }
      __syncthreads();
    }
    #pragma unroll
    for (int m = 0; m < 4; m++)
      #pragma unroll
      for (int n = 0; n < 4; n++)
        #pragma unroll
        for (int j = 0; j < 4; j++)
          out_sh[(size_t)(m0 + wm + m*16 + cr + j) * H_DIM + (n0 + n*16 + cc)] = acc[m][n][j];
  }
}

// ---------------- per-head q/k rmsnorm + rope + v relayout, from fused qkv f32 ----------------
__global__ __launch_bounds__(256) void rope_kernel(
    const float* __restrict__ qkv,
    const float* __restrict__ cosb, const float* __restrict__ sinb,
    const float* __restrict__ qnw, const float* __restrict__ knw,
    u16* __restrict__ qrh, u16* __restrict__ qrl,
    u16* __restrict__ krh, u16* __restrict__ krl,
    u16* __restrict__ vth, u16* __restrict__ vtl)
{
  const int jid = blockIdx.x * 4 + (threadIdx.x >> 6);
  const int lane = threadIdx.x & 63;
  const int t = jid / 24, r = jid - t*24;
  const int b = t >> 10, s = t & (S_LEN - 1);
  const float* row = qkv + (size_t)t * 3072;
  if (r < NHEAD + NKVH) {
    const bool isq = (r < NHEAD);
    const int h = isq ? r : (r - NHEAD);
    const float* x = row + (isq ? h*DHEAD : (2048 + h*DHEAD));
    const float* nw = isq ? qnw : knw;
    float x0 = x[lane], x1 = x[lane + 64];
    float ss = x0*x0 + x1*x1;
    #pragma unroll
    for (int d = 1; d < 64; d <<= 1) ss += __shfl_xor(ss, d, 64);
    float rinv = rsqrtf(ss * (1.0f/DHEAD) + EPSF);
    float n0 = x0*rinv*nw[lane], n1 = x1*rinv*nw[lane + 64];
    float o0 = n0*cosb[s*DHEAD + lane]      - n1*sinb[s*DHEAD + lane];
    float o1 = n1*cosb[s*DHEAD + lane + 64] + n0*sinb[s*DHEAD + lane + 64];
    size_t base = isq ? ((size_t)(b*NHEAD + h)*S_LEN + s)*DHEAD
                      : ((size_t)(b*NKVH + h)*S_LEN + s)*DHEAD;
    u16* dh = isq ? qrh : krh;
    u16* dl = isq ? qrl : krl;
    u16 hh, ll;
    split2(o0, hh, ll); dh[base + lane]      = hh; dl[base + lane]      = ll;
    split2(o1, hh, ll); dh[base + lane + 64] = hh; dl[base + lane + 64] = ll;
  } else {
    const int h = r - NHEAD - NKVH;
    const float* x = row + 2560 + h*DHEAD;
    size_t base = (size_t)(b*NKVH + h)*DHEAD*S_LEN + s;
    u16 hh, ll;
    split2(x[lane], hh, ll);
    vth[base + (size_t)lane*S_LEN] = hh; vtl[base + (size_t)lane*S_LEN] = ll;
    split2(x[lane + 64], hh, ll);
    vth[base + (size_t)(lane + 64)*S_LEN] = hh; vtl[base + (size_t)(lane + 64)*S_LEN] = ll;
  }
}

// ---------------- flash attention, causal, GQA; f16 hi/lo 3-term; PAIRED q-tiles for balance ----------------
__global__ __launch_bounds__(256) void attn_kernel(
    const u16* __restrict__ qrh, const u16* __restrict__ qrl,
    const u16* __restrict__ krh, const u16* __restrict__ krl,
    const u16* __restrict__ vth, const u16* __restrict__ vtl,
    u16* __restrict__ oh, u16* __restrict__ ol)
{
  __shared__ u16 Kh[64*128], Kl[64*128];
  __shared__ u16 Vh[128*64], Vl[128*64];
  __shared__ u16 Ph[4*16*64], Pl[4*16*64];
  const int bx = blockIdx.x, h = blockIdx.y, b = blockIdx.z;
  const int hkv = h >> 2;
  const int lane = threadIdx.x & 63, wave = threadIdx.x >> 6;
  const int fr = lane & 15, fg = lane >> 4;
  const u16* qbh = qrh + ((size_t)(b*NHEAD + h)*S_LEN)*DHEAD;
  const u16* qbl = qrl + ((size_t)(b*NHEAD + h)*S_LEN)*DHEAD;
  const u16* kbh = krh + ((size_t)(b*NKVH + hkv)*S_LEN)*DHEAD;
  const u16* kbl = krl + ((size_t)(b*NKVH + hkv)*S_LEN)*DHEAD;
  const u16* vbh = vth + ((size_t)(b*NKVH + hkv)*DHEAD)*S_LEN;
  const u16* vbl = vtl + ((size_t)(b*NKVH + hkv)*DHEAD)*S_LEN;
  const float scl = 0.08838834764831845f;

  for (int it = 0; it < 2; it++) {
    const int qt = it ? (15 - bx) : bx;
    const int q0 = qt * 64;
    f16x8 aqh[4], aql[4];
    {
      const size_t qrow = (size_t)(q0 + wave*16 + fr)*DHEAD;
      #pragma unroll
      for (int kk = 0; kk < 4; kk++) {
        aqh[kk] = *(const f16x8*)&qbh[qrow + kk*32 + fg*8];
        aql[kk] = *(const f16x8*)&qbl[qrow + kk*32 + fg*8];
      }
    }
    f32x4 o0[8] = {}, o1[8] = {};
    float mrow[4] = {-1e30f,-1e30f,-1e30f,-1e30f};
    float lrow[4] = {0.f,0.f,0.f,0.f};
    for (int jt = 0; jt <= qt; jt++) {
      const int j0 = jt * 64;
      #pragma unroll
      for (int p = 0; p < 4; p++) {
        const int ck = p*4 + wave;
        gload_lds16(kbh + (size_t)(j0 + ck*4 + (lane>>4))*DHEAD + (lane&15)*8, &Kh[ck*512]);
        gload_lds16(kbl + (size_t)(j0 + ck*4 + (lane>>4))*DHEAD + (lane&15)*8, &Kl[ck*512]);
        gload_lds16(vbh + (size_t)(ck*8 + (lane>>3))*S_LEN + j0 + (lane&7)*8, &Vh[ck*512]);
        gload_lds16(vbl + (size_t)(ck*8 + (lane>>3))*S_LEN + j0 + (lane&7)*8, &Vl[ck*512]);
      }
      __syncthreads();
      f32x4 s0[4] = {}, s1[4] = {};
      #pragma unroll
      for (int kk = 0; kk < 4; kk++) {
        const int ko = kk*32 + fg*8;
        #pragma unroll
        for (int n = 0; n < 4; n++) {
          f16x8 bh_ = *(const f16x8*)&Kh[(n*16 + fr)*128 + ko];
          f16x8 bl_ = *(const f16x8*)&Kl[(n*16 + fr)*128 + ko];
          s0[n] = __builtin_amdgcn_mfma_f32_16x16x32_f16(aqh[kk], bh_, s0[n], 0,0,0);
          s1[n] = __builtin_amdgcn_mfma_f32_16x16x32_f16(aqh[kk], bl_, s1[n], 0,0,0);
          s1[n] = __builtin_amdgcn_mfma_f32_16x16x32_f16(aql[kk], bh_, s1[n], 0,0,0);
        }
      }
      const int rb = q0 + wave*16 + fg*4;
      float pv[4][4];
      #pragma unroll
      for (int n = 0; n < 4; n++)
        #pragma unroll
        for (int j = 0; j < 4; j++) {
          float v = (s0[n][j] + s1[n][j]*(1.0f/2048.0f)) * scl;
          if (j0 + n*16 + fr > rb + j) v = -1e30f;
          pv[n][j] = v;
        }
      float alpha[4];
      #pragma unroll
      for (int j = 0; j < 4; j++) {
        float mx = fmaxf(fmaxf(pv[0][j], pv[1][j]), fmaxf(pv[2][j], pv[3][j]));
        #pragma unroll
        for (int d = 1; d < 16; d <<= 1) mx = fmaxf(mx, __shfl_xor(mx, d, 64));
        float mnew = fmaxf(mrow[j], mx);
        alpha[j] = __expf(mrow[j] - mnew);
        mrow[j] = mnew;
      }
      float rsum[4] = {0.f,0.f,0.f,0.f};
      #pragma unroll
      for (int n = 0; n < 4; n++)
        #pragma unroll
        for (int j = 0; j < 4; j++) {
          float p = __expf(pv[n][j] - mrow[j]);
          pv[n][j] = p;
          rsum[j] += p;
        }
      #pragma unroll
      for (int j = 0; j < 4; j++) {
        #pragma unroll
        for (int d = 1; d < 16; d <<= 1) rsum[j] += __shfl_xor(rsum[j], d, 64);
        lrow[j] = lrow[j]*alpha[j] + rsum[j];
      }
      #pragma unroll
      for (int n2 = 0; n2 < 8; n2++)
        #pragma unroll
        for (int j = 0; j < 4; j++) { o0[n2][j] *= alpha[j]; o1[n2][j] *= alpha[j]; }
      #pragma unroll
      for (int n = 0; n < 4; n++)
        #pragma unroll
        for (int j = 0; j < 4; j++) {
          u16 hh, ll; split2(pv[n][j], hh, ll);
          Ph[wave*1024 + (fg*4 + j)*64 + n*16 + fr] = hh;
          Pl[wave*1024 + (fg*4 + j)*64 + n*16 + fr] = ll;
        }
      __syncthreads();
      #pragma unroll
      for (int kk = 0; kk < 2; kk++) {
        const int ko = kk*32 + fg*8;
        f16x8 ah_ = *(const f16x8*)&Ph[wave*1024 + fr*64 + ko];
        f16x8 al_ = *(const f16x8*)&Pl[wave*1024 + fr*64 + ko];
        #pragma unroll
        for (int n2 = 0; n2 < 8; n2++) {
          f16x8 vh_ = *(const f16x8*)&Vh[(n2*16 + fr)*64 + ko];
          f16x8 vl_ = *(const f16x8*)&Vl[(n2*16 + fr)*64 + ko];
          o0[n2] = __builtin_amdgcn_mfma_f32_16x16x32_f16(ah_, vh_, o0[n2], 0,0,0);
          o1[n2] = __builtin_amdgcn_mfma_f32_16x16x32_f16(ah_, vl_, o1[n2], 0,0,0);
          o1[n2] = __builtin_amdgcn_mfma_f32_16x16x32_f16(al_, vh_, o1[n2], 0,0,0);
        }
      }
      __syncthreads();
    }
    float inv[4];
    #pragma unroll
    for (int j = 0; j < 4; j++) inv[j] = 1.0f / lrow[j];
    #pragma unroll
    for (int n2 = 0; n2 < 8; n2++)
      #pragma unroll
      for (int j = 0; j < 4; j++) {
        int s = q0 + wave*16 + fg*4 + j;
        size_t idx = ((size_t)(b*S_LEN + s))*H_DIM + h*DHEAD + n2*16 + fr;
        float val = (o0[n2][j] + o1[n2][j]*(1.0f/2048.0f)) * inv[j];
        u16 hh, ll; split2(val, hh, ll);
        oh[idx] = hh; ol[idx] = ll;
      }
  }
}

// ---------------- router: 256 thr / 4 waves; fused ln2 tok write (wave 0) + 4 logits per wave ----------------
__global__ __launch_bounds__(256) void router_kernel(
    const float* __restrict__ resid, const float* __restrict__ ln2w,
    const float* __restrict__ gw, int* __restrict__ ids, float* __restrict__ wts,
    int* __restrict__ counts, u16* __restrict__ tok)
{
  __shared__ float lgs[NEXP];
  const int t = blockIdx.x, tid = threadIdx.x;
  const int lane = tid & 63, wave = tid >> 6;
  const float* x = resid + (size_t)t * H_DIM;
  float xv[32];
  float ss = 0.f;
  #pragma unroll
  for (int p = 0; p < 8; p++) {
    float4 v  = *(const float4*)&x[p*256 + lane*4];
    float4 lw = *(const float4*)&ln2w[p*256 + lane*4];
    ss += v.x*v.x + v.y*v.y + v.z*v.z + v.w*v.w;
    xv[p*4+0] = v.x*lw.x; xv[p*4+1] = v.y*lw.y; xv[p*4+2] = v.z*lw.z; xv[p*4+3] = v.w*lw.w;
  }
  #pragma unroll
  for (int d = 1; d < 64; d <<= 1) ss += __shfl_xor(ss, d, 64);
  const float rinv = rsqrtf(ss * (1.0f/H_DIM) + EPSF);
  if (wave == 0) {
    u16* tokrow = tok + (size_t)t * H_DIM;
    #pragma unroll
    for (int p = 0; p < 8; p++) {
      u32 lo = (u32)f2h(xv[p*4+0]*rinv) | ((u32)f2h(xv[p*4+1]*rinv) << 16);
      u32 hi = (u32)f2h(xv[p*4+2]*rinv) | ((u32)f2h(xv[p*4+3]*rinv) << 16);
      *(uint2*)&tokrow[p*256 + lane*4] = make_uint2(lo, hi);
    }
  }
  #pragma unroll
  for (int i = 0; i < 4; i++) {
    const int e = wave*4 + i;
    const float* g = gw + (size_t)e * H_DIM;
    float dacc = 0.f;
    #pragma unroll
    for (int p = 0; p < 8; p++) {
      float4 gv = *(const float4*)&g[p*256 + lane*4];
      dacc += xv[p*4+0]*gv.x + xv[p*4+1]*gv.y + xv[p*4+2]*gv.z + xv[p*4+3]*gv.w;
    }
    #pragma unroll
    for (int d = 1; d < 64; d <<= 1) dacc += __shfl_xor(dacc, d, 64);
    if (lane == 0) lgs[e] = dacc * rinv;
  }
  __syncthreads();
  if (tid == 0) {
    float lg[NEXP];
    #pragma unroll
    for (int e = 0; e < NEXP; e++) lg[e] = lgs[e];
    int i0 = 0; float b0 = lg[0];
    #pragma unroll
    for (int e = 1; e < NEXP; e++) if (lg[e] > b0) { b0 = lg[e]; i0 = e; }
    int i1 = -1; float b1 = -3e38f;
    #pragma unroll
    for (int e = 0; e < NEXP; e++) if (e != i0 && lg[e] > b1) { b1 = lg[e]; i1 = e; }
    float rr = __expf(b1 - b0);
    float w0 = 1.0f / (1.0f + rr);
    ids[t*2] = i0; ids[t*2+1] = i1;
    wts[t*2] = w0; wts[t*2+1] = rr * w0;
    atomicAdd(&counts[i0], 1);
    atomicAdd(&counts[i1], 1);
  }
}

__global__ void scan_kernel(const int* __restrict__ counts, int* __restrict__ offs,
                            int* __restrict__ cursor,
                            int* __restrict__ tile_e, int* __restrict__ tile_m0)
{
  if (threadIdx.x == 0) {
    int s = 0, nt = 0;
    for (int e = 0; e < NEXP; e++) {
      offs[e] = s; cursor[e] = 0;
      int c = counts[e];
      for (int m0 = 0; m0 < c; m0 += 256) { tile_e[nt] = e; tile_m0[nt] = m0; nt++; }
      s += c;
    }
    for (; nt < 32; nt++) { tile_e[nt] = -1; tile_m0[nt] = 0; }
  }
}

__global__ __launch_bounds__(256) void scatter_kernel(
    const int* __restrict__ ids, const int* __restrict__ offs,
    int* __restrict__ cursor, int* __restrict__ list, int* __restrict__ pos)
{
  int t = blockIdx.x * 256 + threadIdx.x;
  if (t < T_TOK) {
    for (int kk = 0; kk < 2; kk++) {
      int e = ids[t*2 + kk];
      int p = atomicAdd(&cursor[e], 1);
      int i = offs[e] + p;
      list[i] = t;
      pos[t*2 + kk] = i;
    }
  }
}

// ---------------- silu_all: expert rows (0..4095) + shared rows (4096..6143) ----------------
__global__ __launch_bounds__(256) void silu_all_kernel(
    const float* __restrict__ gu_exp, u16* __restrict__ act_ex,
    const float* __restrict__ gu_sh,  u16* __restrict__ act_sh)
{
  const int rr = blockIdx.x;
  const float* g;
  u16* o;
  if (rr < 2*T_TOK) { g = gu_exp + (size_t)rr * FF2;          o = act_ex + (size_t)rr * FFE; }
  else              { g = gu_sh  + (size_t)(rr - 2*T_TOK) * FF2; o = act_sh + (size_t)(rr - 2*T_TOK) * FFE; }
  for (int c = threadIdx.x*4; c < FFE; c += 1024) {
    float4 gv = *(const float4*)&g[c];
    float4 uv = *(const float4*)&g[c + FFE];
    float s0 = gv.x / (1.0f + __expf(-gv.x)) * uv.x;
    float s1 = gv.y / (1.0f + __expf(-gv.y)) * uv.y;
    float s2 = gv.z / (1.0f + __expf(-gv.z)) * uv.z;
    float s3 = gv.w / (1.0f + __expf(-gv.w)) * uv.w;
    u32 lo = (u32)f2h(s0) | ((u32)f2h(s1) << 16);
    u32 hi = (u32)f2h(s2) | ((u32)f2h(s3) << 16);
    *(uint2*)&o[c] = make_uint2(lo, hi);
  }
}

// out = out(shared) + w0*y[p0] + w1*y[p1]   (in-place RMW on d_out)
__global__ __launch_bounds__(256) void combine_kernel(
    const float* __restrict__ y,
    const int* __restrict__ pos, const float* __restrict__ wts,
    float* __restrict__ out)
{
  const int t = blockIdx.x;
  const int p0 = pos[t*2], p1 = pos[t*2+1];
  const float w0 = wts[t*2] * RSF_C, w1 = wts[t*2+1] * RSF_C;
  const int c = threadIdx.x * 8;
  #pragma unroll
  for (int q = 0; q < 2; q++) {
    const int cc = c + q*4;
    float4 s  = *(const float4*)&out[(size_t)t*H_DIM + cc];
    float4 a  = *(const float4*)&y[(size_t)p0*H_DIM + cc];
    float4 bb = *(const float4*)&y[(size_t)p1*H_DIM + cc];
    float4 r;
    r.x = s.x + w0*a.x + w1*bb.x;
    r.y = s.y + w0*a.y + w1*bb.y;
    r.z = s.z + w0*a.z + w1*bb.z;
    r.w = s.w + w0*a.w + w1*bb.w;
    *(float4*)&out[(size_t)t*H_DIM + cc] = r;
  }
}

extern "C" void kernel_launch(void* const* d_in, const int* in_sizes, int n_in,
                              void* d_out, int out_size, void* d_ws, size_t ws_size,
                              hipStream_t stream)
{
  (void)in_sizes; (void)n_in; (void)out_size;
  const float* hidden = (const float*)d_in[0];
  const float* cosb   = (const float*)d_in[1];
  const float* sinb   = (const float*)d_in[2];
  const float* ln1w   = (const float*)d_in[3];
  const float* ln2w   = (const float*)d_in[4];
  const float* qnw    = (const float*)d_in[5];
  const float* knw    = (const float*)d_in[6];
  const float* wq     = (const float*)d_in[7];
  const float* wk     = (const float*)d_in[8];
  const float* wv     = (const float*)d_in[9];
  const float* wo     = (const float*)d_in[10];
  const float* gw     = (const float*)d_in[11];
  const float* egu    = (const float*)d_in[12];
  const float* edn    = (const float*)d_in[13];
  const float* sgu    = (const float*)d_in[14];
  const float* sdn    = (const float*)d_in[15];
  float* out_hidden = (float*)d_out;
  float* resid = (float*)d_out + (size_t)T_TOK * H_DIM;

  char* ws = (char*)d_ws;
  // ---- phase A (pre-router) ----
  constexpr size_t OFF_XH    = 0;
  constexpr size_t OFF_XL    = 8388608;
  constexpr size_t OFF_WQKVH = 16777216;
  constexpr size_t OFF_WQKVL = 29360128;
  constexpr size_t OFF_WOH   = 41943040;
  constexpr size_t OFF_WOL   = 50331648;
  constexpr size_t OFF_QKV   = 58720256;   // 25,165,824 f32 [2048][3072]
  constexpr size_t OFF_QRH = 16777216, OFF_QRL = 25165824;
  constexpr size_t OFF_KRH = 33554432, OFF_KRL = 35651584;
  constexpr size_t OFF_VTH = 37748736, OFF_VTL = 39845888;
  constexpr size_t OFF_OH = 58720256, OFF_OL = 67108864;
  // ---- phase B (post-router) ----
  constexpr size_t OFF_GUE = 0;            // gu_exp 46,137,344 ; later y_exp 33,554,432
  constexpr size_t OFF_TOK = 63963136;     // 8,388,608
  constexpr size_t OFF_ACE = 72351744;     // act_ex (4096+256)x1408x2 = 12,255,232
  constexpr size_t OFF_GUS = 84606976;     // 23,068,672
  constexpr size_t OFF_ACS = 107675648;    // 5,767,168
  constexpr size_t OFF_SGUT= 113442816;    // 11,534,336
  constexpr size_t OFF_SDNT= 124977152;    // 5,767,168
  constexpr size_t OFF_IDS = 130744320;
  constexpr size_t OFF_WTS = OFF_IDS + 16384;
  constexpr size_t OFF_POS = OFF_WTS + 16384;
  constexpr size_t OFF_LST = OFF_POS + 16384;
  constexpr size_t OFF_CNT = OFF_LST + 16384;
  constexpr size_t OFF_OFS = OFF_CNT + 64;
  constexpr size_t OFF_CUR = OFF_OFS + 64;
  constexpr size_t OFF_TE  = OFF_CUR + 64;
  constexpr size_t OFF_TM  = OFF_TE + 128;
  constexpr size_t WS_NEED = OFF_TM + 128;
  if (ws_size < WS_NEED) return;

  u16* xh     = (u16*)(ws + OFF_XH);
  u16* xl     = (u16*)(ws + OFF_XL);
  u16* wqkvh  = (u16*)(ws + OFF_WQKVH);
  u16* wqkvl  = (u16*)(ws + OFF_WQKVL);
  u16* woh    = (u16*)(ws + OFF_WOH);
  u16* wol    = (u16*)(ws + OFF_WOL);
  float* qkv  = (float*)(ws + OFF_QKV);
  u16* q_rh = (u16*)(ws + OFF_QRH);
  u16* q_rl = (u16*)(ws + OFF_QRL);
  u16* k_rh = (u16*)(ws + OFF_KRH);
  u16* k_rl = (u16*)(ws + OFF_KRL);
  u16* v_th = (u16*)(ws + OFF_VTH);
  u16* v_tl = (u16*)(ws + OFF_VTL);
  u16* o_h  = (u16*)(ws + OFF_OH);
  u16* o_l  = (u16*)(ws + OFF_OL);
  float* gu_exp = (float*)(ws + OFF_GUE);
  float* y_exp  = (float*)(ws + OFF_GUE);
  u16* tok      = (u16*)(ws + OFF_TOK);
  u16* act_ex   = (u16*)(ws + OFF_ACE);
  float* gu_sh  = (float*)(ws + OFF_GUS);
  u16* act_sh   = (u16*)(ws + OFF_ACS);
  u16* sgut     = (u16*)(ws + OFF_SGUT);
  u16* sdnt     = (u16*)(ws + OFF_SDNT);
  int* ids    = (int*)(ws + OFF_IDS);
  float* wts  = (float*)(ws + OFF_WTS);
  int* pos    = (int*)(ws + OFF_POS);
  int* list   = (int*)(ws + OFF_LST);
  int* counts = (int*)(ws + OFF_CNT);
  int* offs   = (int*)(ws + OFF_OFS);
  int* cursor = (int*)(ws + OFF_CUR);
  int* tile_e = (int*)(ws + OFF_TE);
  int* tile_m0= (int*)(ws + OFF_TM);

  hipMemsetAsync(counts, 0, 64, stream);

  // ---- prep: all weight transpose/split jobs in ONE launch ----
  tsplit_all_kernel<<<dim3(44,32,6), 256, 0, stream>>>(wq, wk, wv, wo, sgu, sdn,
                                                       wqkvh, wqkvl, woh, wol, sgut, sdnt);

  // ---- pre-router chain (f16 hi/lo precision) ----
  rmsnorm_kernel<<<T_TOK, 256, 0, stream>>>(hidden, ln1w, xh, xl);
  gemm3b96_kernel<<<dim3(32,16), 256, 0, stream>>>(xh, xl, H_DIM, wqkvh, wqkvl, 2048, qkv, 3072, H_DIM);
  rope_kernel<<<(T_TOK*24)/4, 256, 0, stream>>>(qkv, cosb, sinb, qnw, knw,
                                                q_rh, q_rl, k_rh, k_rl, v_th, v_tl);
  attn_kernel<<<dim3(8, NHEAD, NB), 256, 0, stream>>>(q_rh, q_rl, k_rh, k_rl, v_th, v_tl, o_h, o_l);
  gemm3b_kernel<<<dim3(16,16), 256, 0, stream>>>(o_h, o_l, H_DIM, woh, wol, 2048, resid, H_DIM, hidden, H_DIM);

  // ---- router (fused ln2 -> tok, 4-wave) ----
  router_kernel<<<T_TOK, 256, 0, stream>>>(resid, ln2w, gw, ids, wts, counts, tok);
  scan_kernel<<<1, 64, 0, stream>>>(counts, offs, cursor, tile_e, tile_m0);
  scatter_kernel<<<8, 256, 0, stream>>>(ids, offs, cursor, list, pos);

  // ---- MoE: merged up (indirect A from tok via list -- no gather), merged silu, merged down, combine ----
  gemm_up_all_kernel<<<dim3(44,1,40), 256, 0, stream>>>(list, egu, gu_exp,
                                                        counts, offs, tile_e, tile_m0,
                                                        tok, sgut, gu_sh);
  silu_all_kernel<<<3*T_TOK, 256, 0, stream>>>(gu_exp, act_ex, gu_sh, act_sh);
  gemm_dn_all_kernel<<<dim3(32,1,40), 256, 0, stream>>>(act_ex, edn, y_exp,
                                                        counts, offs, tile_e, tile_m0,
                                                        act_sh, sdnt, out_hidden);
  combine_kernel<<<T_TOK, 256, 0, stream>>>(y_exp, pos, wts, out_hidden);
}